// Round 5
// baseline (578.137 us; speedup 1.0000x reference)
//
#include <hip/hip_runtime.h>
#include <math.h>

// Problem constants (B,T,H,K,V,BT) = (2,8192,16,32,64,64)
#define Tt 8192
#define Hh 16
#define NCH 4096        // chunk-heads, ch = c*32 + (b*16+h)
// Workspace layout (floats):
//   wsW  [NCH][2048]  w (64x32 row-major)
//   wsU  [NCH][4096]  u (64x64 row-major)
//   wsM  [NCH][1024]  M = diag(egl) - Kd^T W
//   wsC  [NCH][2048]  C = Kd^T U   -> overwritten by entering-S (32x64) in scanC
//   wsMs [256][1024]  per-segment composed M
//   wsCs [256][2048]  per-segment composed C
//   wsSs [256][2048]  entering S per segment

#define OFF_U   ((size_t)NCH*2048)
#define OFF_M   ((size_t)NCH*6144)
#define OFF_C   ((size_t)NCH*7168)
#define OFF_MS  ((size_t)NCH*9216)
#define OFF_CS  (OFF_MS + (size_t)256*1024)
#define OFF_SS  (OFF_CS + (size_t)256*2048)

__device__ __forceinline__ float softplusf(float x) {
  return fmaxf(x, 0.f) + log1pf(__expf(-fabsf(x)));
}

// blk(p,q) = p*(p+1)/2 + q for p>=q (10 blocks of a 4x4 block-triangle)

// ---------------- Phase 1 ----------------
// 256 threads. LDS diet: 53.8KB -> 40.2KB => 4 blocks/CU (16 waves) vs 3 (12).
// L packed 10x256 (in-block [col][row]); Tm packed 10x272 (in-block [row]*17+[col],
// conflict-free per-lane-iq reads); Tm overlays dead P/Qb; vb/u/C in two 32-col halves.
__global__ __launch_bounds__(256) void kda_phase1(
    const float* __restrict__ kin, const float* __restrict__ vin,
    const float* __restrict__ graw, const float* __restrict__ beta,
    const float* __restrict__ A_log, const float* __restrict__ dt_bias,
    float* __restrict__ ws)
{
  __shared__ float sG[64*33];   // gcum (s33) -> w (s32, 2048)
  __shared__ float sK[64*33];   // kn -> kd (s33)
  __shared__ float sU[2720];    // P(2304,s36)+Qb(256 @2304) -> Tm-packed (10x272)
  __shared__ float sW[3104];    // L-packed(10x256) + sC2(2x272 @2560) -> k_egb(2048) -> vb/u-half(2048); Egl @3072

  const int tid = threadIdx.x;
  const int ch = blockIdx.x;
  const int c = ch >> 5, bh = ch & 31;
  const int b = bh >> 4, h = bh & 15;
  const int t0 = c*64;
  const int iq = tid >> 2, kq = (tid & 3)*8;

  float* wsW = ws;
  float* wsU = ws + OFF_U;
  float* wsM = ws + OFF_M;
  float* wsCc= ws + OFF_C;

  const float negA = -__expf(A_log[h]);

  { // gate g into sG
    const float* gr = graw + (((size_t)b*Tt + t0 + iq)*Hh + h)*32 + kq;
    const float* db = dt_bias + h*32 + kq;
    #pragma unroll
    for (int r = 0; r < 8; ++r)
      sG[iq*33 + kq + r] = negA * softplusf(gr[r] + db[r]);
  }
  __syncthreads();
  if (tid < 32) { // register-chunked cumsum over time per k
    float c0 = 0.f;
    for (int blk = 0; blk < 4; ++blk) {
      float v[16];
      #pragma unroll
      for (int i = 0; i < 16; ++i) v[i] = sG[(blk*16+i)*33 + tid];
      #pragma unroll
      for (int i = 0; i < 16; ++i) { c0 += v[i]; sG[(blk*16+i)*33 + tid] = c0; }
    }
  }
  { // k row-l2-normalize into sK
    const float* kp = kin + (((size_t)b*Tt + t0 + iq)*Hh + h)*32 + kq;
    float kr[8]; float ss = 0.f;
    #pragma unroll
    for (int r = 0; r < 8; ++r) { kr[r] = kp[r]; ss += kr[r]*kr[r]; }
    ss += __shfl_xor(ss, 1); ss += __shfl_xor(ss, 2);
    const float sc = 1.f / fmaxf(sqrtf(ss), 1e-6f);
    #pragma unroll
    for (int r = 0; r < 8; ++r) sK[iq*33 + kq + r] = kr[r]*sc;
  }
  __syncthreads();

  // ---- Akk tiles -> L packed ----
  const float b_cm = beta[((size_t)b*Tt + t0 + (tid & 63))*Hh + h];
  float* P  = sU;          // 64x36
  float* Qb = sU + 2304;   // 8x32
  const int i64 = tid & 63, jj2 = (tid >> 6)*2;
  const int pL = i64 >> 4, pLb = pL*(pL+1)/2, iL = i64 & 15;
  for (int jt = 0; jt < 8; ++jt) {
    const int j0 = jt*8;
    {
      float pv[8];
      #pragma unroll
      for (int r = 0; r < 8; ++r) {
        const int idx = iq*33 + kq + r;
        pv[r] = sK[idx] * __expf(fminf(sG[idx] - sG[j0*33 + kq + r], 0.f));
      }
      *(float4*)(P + iq*36 + kq)     = make_float4(pv[0],pv[1],pv[2],pv[3]);
      *(float4*)(P + iq*36 + kq + 4) = make_float4(pv[4],pv[5],pv[6],pv[7]);
    }
    {
      const int jj = tid >> 5, kk = tid & 31;
      Qb[jj*32 + kk] = sK[(j0+jj)*33 + kk] * __expf(sG[j0*33 + kk] - sG[(j0+jj)*33 + kk]);
    }
    __syncthreads();
    float a0 = 0.f, a1 = 0.f;
    #pragma unroll
    for (int hf = 0; hf < 2; ++hf) {
      const int k0 = hf*16;
      #pragma unroll
      for (int t4 = 0; t4 < 4; ++t4) {
        const float4 pa = *(const float4*)(P  + i64*36 + k0 + t4*4);
        const float4 xa = *(const float4*)(Qb + (jj2  )*32 + k0 + t4*4);
        const float4 xb = *(const float4*)(Qb + (jj2+1)*32 + k0 + t4*4);
        a0 += pa.x*xa.x + pa.y*xa.y + pa.z*xa.z + pa.w*xa.w;
        a1 += pa.x*xb.x + pa.y*xb.y + pa.z*xb.z + pa.w*xb.w;
      }
    }
    const int j_0 = j0 + jj2;
    const int qB = j_0 >> 4;
    if (pL >= qB) {   // only lower blocks stored
      float* Lb = sW + (pLb + qB)*256 + iL;
      Lb[((j_0  ) & 15)*16] = (i64 > j_0  ) ? a0*b_cm : 0.f;
      Lb[((j_0+1) & 15)*16] = (i64 > j_0+1) ? a1*b_cm : 0.f;
    }
    __syncthreads();
  }

  // ---- Tm = (I+L)^-1: diag blocks (row0 seed + lane-local forward-sub) ----
  if (tid < 64) {
    const int p = tid >> 4, col = tid & 15;
    const int bD = p*(p+1)/2 + p;
    float* Td = sU + bD*272;
    const float* Ld = sW + bD*256;
    Td[col] = (col == 0) ? 1.f : 0.f;   // row 0
    for (int i = 1; i < 16; ++i) {
      float acc = 0.f;
      for (int j = 0; j < i; ++j)
        acc -= Ld[j*16 + i] * Td[j*17 + col];
      Td[i*17 + col] = acc + ((i == col) ? 1.f : 0.f);
    }
  }
  __syncthreads();
  // off-diagonal: 2 waves x 3 rounds; deps: each consumed Tm block done a round earlier
  {
    const int wid = tid >> 6;
    const int lane = tid & 63;
    const int ri = lane & 15, c4 = (lane >> 4)*4;
    float* Ct = sW + 2560 + wid*272;
    auto offblk = [&](int p, int q) {
      const int pb = p*(p+1)/2;
      float a0=0.f, a1=0.f, a2=0.f, a3=0.f;
      for (int m = q; m < p; ++m) {
        const float* Lb = sW + (pb + m)*256;
        const float* Tb = sU + (m*(m+1)/2 + q)*272;
        #pragma unroll
        for (int j = 0; j < 16; ++j) {
          const float lv = Lb[j*16 + ri];
          const float* tp = Tb + j*17 + c4;
          a0 += lv*tp[0]; a1 += lv*tp[1]; a2 += lv*tp[2]; a3 += lv*tp[3];
        }
      }
      float* cp = Ct + ri*17 + c4;
      cp[0]=a0; cp[1]=a1; cp[2]=a2; cp[3]=a3;
      const float* Tpp = sU + (pb + p)*272 + ri*17;
      float b0=0.f, b1=0.f, b2=0.f, b3=0.f;
      #pragma unroll
      for (int j = 0; j < 16; ++j) {
        const float tv = Tpp[j];
        const float* cj = Ct + j*17 + c4;
        b0 += tv*cj[0]; b1 += tv*cj[1]; b2 += tv*cj[2]; b3 += tv*cj[3];
      }
      float* op = sU + (pb + q)*272 + ri*17 + c4;
      op[0]=-b0; op[1]=-b1; op[2]=-b2; op[3]=-b3;
    };
    if (wid == 0) offblk(1,0); else if (wid == 1) offblk(2,1);
    __syncthreads();
    if (wid == 0) offblk(2,0); else if (wid == 1) offblk(3,1);
    __syncthreads();
    if (wid == 0) offblk(3,0); else if (wid == 1) offblk(3,2);
  }
  __syncthreads();

  { // k_egb into sW[0..2048); kd -> sK; Egl @ sW+3072
    const float b_row = beta[((size_t)b*Tt + t0 + iq)*Hh + h];
    #pragma unroll
    for (int r = 0; r < 8; ++r) {
      const int idx = iq*33 + kq + r;
      const float g = sG[idx], kn = sK[idx];
      sW[iq*32 + kq + r] = b_row * kn * __expf(g);
      sK[idx] = kn * __expf(sG[63*33 + kq + r] - g);
    }
    if (tid < 32) sW[3072 + tid] = __expf(sG[63*33 + tid]);
  }
  __syncthreads();

  const int pT = iq >> 4, pTb = pT*(pT+1)/2;
  const int r17 = (iq & 15)*17, iqm = iq & 15;

  { // w = Tm @ k_egb -> global + sG (gcum dead)
    float acc[8] = {0,0,0,0,0,0,0,0};
    for (int m = 0; m <= pT; ++m) {
      const float* Tb = sU + (pTb + m)*272 + r17;
      const int jmax = (m == pT) ? iqm : 15;
      const float* eb = sW + m*16*32 + kq;
      for (int jj = 0; jj <= jmax; ++jj) {
        const float t = Tb[jj];
        const float4 e0 = *(const float4*)(eb + jj*32);
        const float4 e1 = *(const float4*)(eb + jj*32 + 4);
        acc[0]+=t*e0.x; acc[1]+=t*e0.y; acc[2]+=t*e0.z; acc[3]+=t*e0.w;
        acc[4]+=t*e1.x; acc[5]+=t*e1.y; acc[6]+=t*e1.z; acc[7]+=t*e1.w;
      }
    }
    #pragma unroll
    for (int r = 0; r < 8; ++r) {
      wsW[(size_t)ch*2048 + tid*8 + r] = acc[r];
      sG[iq*32 + kq + r] = acc[r];
    }
  }
  __syncthreads();   // k_egb reads done; w visible

  const int vs8 = (tid & 3)*8;
  for (int vh = 0; vh < 2; ++vh) {
    { // stage vb-half (64 x 32 cols)
      #pragma unroll
      for (int r = 0; r < 2; ++r) {
        const int f = tid + 256*r;
        const int j = f >> 3, cc = (f & 7)*4;
        const float bj = beta[((size_t)b*Tt + t0 + j)*Hh + h];
        float4 v4 = *(const float4*)(vin + (((size_t)b*Tt + t0 + j)*Hh + h)*64 + vh*32 + cc);
        v4.x *= bj; v4.y *= bj; v4.z *= bj; v4.w *= bj;
        *(float4*)(sW + j*32 + cc) = v4;
      }
    }
    __syncthreads();
    float ua[8];
    { // u-half = Tm @ vb-half -> wsU
      #pragma unroll
      for (int r = 0; r < 8; ++r) ua[r] = 0.f;
      for (int m = 0; m <= pT; ++m) {
        const float* Tb = sU + (pTb + m)*272 + r17;
        const int jmax = (m == pT) ? iqm : 15;
        const float* eb = sW + m*16*32 + vs8;
        for (int jj = 0; jj <= jmax; ++jj) {
          const float t = Tb[jj];
          const float4 e0 = *(const float4*)(eb + jj*32);
          const float4 e1 = *(const float4*)(eb + jj*32 + 4);
          ua[0]+=t*e0.x; ua[1]+=t*e0.y; ua[2]+=t*e0.z; ua[3]+=t*e0.w;
          ua[4]+=t*e1.x; ua[5]+=t*e1.y; ua[6]+=t*e1.z; ua[7]+=t*e1.w;
        }
      }
      *(float4*)(wsU + (size_t)ch*4096 + iq*64 + vh*32 + vs8)     = make_float4(ua[0],ua[1],ua[2],ua[3]);
      *(float4*)(wsU + (size_t)ch*4096 + iq*64 + vh*32 + vs8 + 4) = make_float4(ua[4],ua[5],ua[6],ua[7]);
    }
    __syncthreads();   // all vb reads done
    *(float4*)(sW + iq*32 + vs8)     = make_float4(ua[0],ua[1],ua[2],ua[3]);
    *(float4*)(sW + iq*32 + vs8 + 4) = make_float4(ua[4],ua[5],ua[6],ua[7]);
    __syncthreads();
    if (vh == 0) { // M = diag(egl) - Kd^T W (once)
      const int a = tid >> 3, b4 = (tid & 7)*4;
      float mA[4] = {0.f,0.f,0.f,0.f};
      for (int t = 0; t < 64; ++t) {
        const float kd = sK[t*33 + a];
        const float4 wv = *(const float4*)(sG + t*32 + b4);
        mA[0]+=kd*wv.x; mA[1]+=kd*wv.y; mA[2]+=kd*wv.z; mA[3]+=kd*wv.w;
      }
      const float eg = sW[3072 + a];
      float4 m4;
      m4.x = ((a == b4+0) ? eg : 0.f) - mA[0];
      m4.y = ((a == b4+1) ? eg : 0.f) - mA[1];
      m4.z = ((a == b4+2) ? eg : 0.f) - mA[2];
      m4.w = ((a == b4+3) ? eg : 0.f) - mA[3];
      *(float4*)(wsM + (size_t)ch*1024 + tid*4) = m4;
    }
    { // C-half = Kd^T U-half
      const int a = tid >> 3, c4c = (tid & 7)*4;
      float cA[4] = {0.f,0.f,0.f,0.f};
      for (int t = 0; t < 64; ++t) {
        const float kd = sK[t*33 + a];
        const float4 u4 = *(const float4*)(sW + t*32 + c4c);
        cA[0]+=kd*u4.x; cA[1]+=kd*u4.y; cA[2]+=kd*u4.z; cA[3]+=kd*u4.w;
      }
      *(float4*)(wsCc + (size_t)ch*2048 + a*64 + vh*32 + c4c) = make_float4(cA[0],cA[1],cA[2],cA[3]);
    }
    __syncthreads();   // C reads done before next stage
  }
}

// ---------------- scanA ----------------
__global__ __launch_bounds__(256) void kda_scanA(float* __restrict__ ws)
{
  __shared__ float sMa[32*33];
  __shared__ float sMc[32*33];
  __shared__ float sCa[32*18];
  const int tid = threadIdx.x;
  const int vt = blockIdx.x & 3, seg = (blockIdx.x >> 2) & 7, bh = blockIdx.x >> 5;
  const int v0 = vt*16;
  const int a = tid >> 3, b4 = (tid & 7)*4, c2 = (tid & 7)*2;
  const float* wsM = ws + OFF_M;
  const float* wsC = ws + OFF_C;

  #pragma unroll
  for (int r = 0; r < 4; ++r) sMa[a*33 + b4 + r] = (a == b4 + r) ? 1.f : 0.f;
  sCa[a*18 + c2] = 0.f; sCa[a*18 + c2 + 1] = 0.f;

  int ch = (seg*16)*32 + bh;
  float4 m4 = *(const float4*)(wsM + (size_t)ch*1024 + tid*4);
  float2 cc = *(const float2*)(wsC + (size_t)ch*2048 + a*64 + v0 + c2);

  for (int i = 0; i < 16; ++i) {
    sMc[a*33+b4+0]=m4.x; sMc[a*33+b4+1]=m4.y; sMc[a*33+b4+2]=m4.z; sMc[a*33+b4+3]=m4.w;
    __syncthreads();
    float4 m4n = m4; float2 ccn = cc;
    if (i < 15) {
      const int chn = (seg*16 + i + 1)*32 + bh;
      m4n = *(const float4*)(wsM + (size_t)chn*1024 + tid*4);
      ccn = *(const float2*)(wsC + (size_t)chn*2048 + a*64 + v0 + c2);
    }
    float cn0 = cc.x, cn1 = cc.y;
    float mn0=0.f, mn1=0.f, mn2=0.f, mn3=0.f;
    for (int bb = 0; bb < 32; ++bb) {
      const float m = sMc[a*33 + bb];
      const float2 s2 = *(const float2*)(sCa + bb*18 + c2);
      cn0 += m*s2.x; cn1 += m*s2.y;
      mn0 += m*sMa[bb*33+b4+0]; mn1 += m*sMa[bb*33+b4+1];
      mn2 += m*sMa[bb*33+b4+2]; mn3 += m*sMa[bb*33+b4+3];
    }
    __syncthreads();
    sCa[a*18+c2] = cn0; sCa[a*18+c2+1] = cn1;
    sMa[a*33+b4+0]=mn0; sMa[a*33+b4+1]=mn1; sMa[a*33+b4+2]=mn2; sMa[a*33+b4+3]=mn3;
    m4 = m4n; cc = ccn;
  }
  const size_t sid = (size_t)(bh*8 + seg);
  float* wsMs = ws + OFF_MS;
  float* wsCs = ws + OFF_CS;
  if (vt == 0) {
    #pragma unroll
    for (int r = 0; r < 4; ++r) wsMs[sid*1024 + tid*4 + r] = sMa[a*33+b4+r];
  }
  float2 co; co.x = sCa[a*18+c2]; co.y = sCa[a*18+c2+1];
  *(float2*)(wsCs + sid*2048 + a*64 + v0 + c2) = co;
}

// ---------------- scanB ----------------
__global__ __launch_bounds__(256) void kda_scanB(float* __restrict__ ws)
{
  __shared__ float sS[32*18];
  __shared__ float sM[32*33];
  const int tid = threadIdx.x;
  const int vt = blockIdx.x & 3, bh = blockIdx.x >> 2;
  const int v0 = vt*16;
  const int a = tid >> 3, b4 = (tid & 7)*4, c2 = (tid & 7)*2;
  const float* wsMs = ws + OFF_MS;
  const float* wsCs = ws + OFF_CS;
  float* wsSs = ws + OFF_SS;

  float s0 = 0.f, s1 = 0.f;
  sS[a*18 + c2] = 0.f; sS[a*18 + c2 + 1] = 0.f;
  const size_t sid0 = (size_t)(bh*8);
  float4 m4 = *(const float4*)(wsMs + sid0*1024 + tid*4);
  float2 cc = *(const float2*)(wsCs + sid0*2048 + a*64 + v0 + c2);

  for (int seg = 0; seg < 8; ++seg) {
    const size_t sid = (size_t)(bh*8 + seg);
    *(float2*)(wsSs + sid*2048 + a*64 + v0 + c2) = make_float2(s0, s1);
    sM[a*33+b4+0]=m4.x; sM[a*33+b4+1]=m4.y; sM[a*33+b4+2]=m4.z; sM[a*33+b4+3]=m4.w;
    __syncthreads();
    float4 m4n = m4; float2 ccn = cc;
    if (seg < 7) {
      m4n = *(const float4*)(wsMs + (sid+1)*1024 + tid*4);
      ccn = *(const float2*)(wsCs + (sid+1)*2048 + a*64 + v0 + c2);
    }
    float n0 = cc.x, n1 = cc.y;
    for (int bb = 0; bb < 32; ++bb) {
      const float m = sM[a*33 + bb];
      const float2 s2 = *(const float2*)(sS + bb*18 + c2);
      n0 += m*s2.x; n1 += m*s2.y;
    }
    __syncthreads();
    s0 = n0; s1 = n1;
    sS[a*18+c2] = s0; sS[a*18+c2+1] = s1;
    m4 = m4n; cc = ccn;
  }
}

// ---------------- scanC ----------------
__global__ __launch_bounds__(256) void kda_scanC(float* __restrict__ ws)
{
  __shared__ float sM[32*33];
  __shared__ float sS[32*18];
  const int tid = threadIdx.x;
  const int vt = blockIdx.x & 3, seg = (blockIdx.x >> 2) & 7, bh = blockIdx.x >> 5;
  const int v0 = vt*16;
  const int a = tid >> 3, b4 = (tid & 7)*4, c2 = (tid & 7)*2;
  const float* wsM = ws + OFF_M;
  float* wsC = ws + OFF_C;
  const float* wsSs = ws + OFF_SS;

  const size_t sid = (size_t)(bh*8 + seg);
  float s0, s1;
  {
    float2 sv = *(const float2*)(wsSs + sid*2048 + a*64 + v0 + c2);
    s0 = sv.x; s1 = sv.y;
    sS[a*18 + c2] = s0; sS[a*18 + c2 + 1] = s1;
  }
  int ch = (seg*16)*32 + bh;
  float4 m4 = *(const float4*)(wsM + (size_t)ch*1024 + tid*4);
  float2 cc = *(const float2*)(wsC + (size_t)ch*2048 + a*64 + v0 + c2);

  for (int i = 0; i < 16; ++i) {
    const int chc = (seg*16 + i)*32 + bh;
    sM[a*33+b4+0]=m4.x; sM[a*33+b4+1]=m4.y; sM[a*33+b4+2]=m4.z; sM[a*33+b4+3]=m4.w;
    *(float2*)(wsC + (size_t)chc*2048 + a*64 + v0 + c2) = make_float2(s0, s1);
    __syncthreads();
    float4 m4n = m4; float2 ccn = cc;
    if (i < 15) {
      const int chn = (seg*16 + i + 1)*32 + bh;
      m4n = *(const float4*)(wsM + (size_t)chn*1024 + tid*4);
      ccn = *(const float2*)(wsC + (size_t)chn*2048 + a*64 + v0 + c2);
    }
    float n0 = cc.x, n1 = cc.y;
    for (int bb = 0; bb < 32; ++bb) {
      const float m = sM[a*33 + bb];
      const float2 s2 = *(const float2*)(sS + bb*18 + c2);
      n0 += m*s2.x; n1 += m*s2.y;
    }
    __syncthreads();
    s0 = n0; s1 = n1;
    sS[a*18+c2] = s0; sS[a*18+c2+1] = s1;
    m4 = m4n; cc = ccn;
  }
}

// ---------------- Phase 3 ----------------
// Same diet: Aqk packed 10x272 (inclusive diag); w/u in sV; o-loop in 2 col-passes.
// LDS 49.9KB -> 38.0KB => 4 blocks/CU.
__global__ __launch_bounds__(256) void kda_phase3(
    const float* __restrict__ qin, const float* __restrict__ kin,
    const float* __restrict__ graw,
    const float* __restrict__ A_log, const float* __restrict__ dt_bias,
    const float* __restrict__ ws, float* __restrict__ out)
{
  __shared__ float sG[64*33];   // gcum (s33) -> S (32x64, 2048)
  __shared__ float sQ[64*33];   // qn -> qeff
  __shared__ float sA[2720];    // Aqk packed (10x272)
  __shared__ float sV[2560];    // P(2304,s36)+Qb(@2304) -> w(2048) -> u-half(2048)

  const int tid = threadIdx.x;
  const int ch = blockIdx.x;
  const int c = ch >> 5, bh = ch & 31;
  const int b = bh >> 4, h = bh & 15;
  const int t0 = c*64;
  const int iq = tid >> 2, kq = (tid & 3)*8;

  const float* wsW = ws;            // w (64x32)
  const float* wsU = ws + OFF_U;    // u (64x64)
  const float* wsS = ws + OFF_C;    // entering S (32x64)

  const float negA = -__expf(A_log[h]);
  {
    const float* gr = graw + (((size_t)b*Tt + t0 + iq)*Hh + h)*32 + kq;
    const float* db = dt_bias + h*32 + kq;
    #pragma unroll
    for (int r = 0; r < 8; ++r)
      sG[iq*33 + kq + r] = negA * softplusf(gr[r] + db[r]);
  }
  __syncthreads();
  if (tid < 32) {
    float c0 = 0.f;
    for (int blk = 0; blk < 4; ++blk) {
      float v[16];
      #pragma unroll
      for (int i = 0; i < 16; ++i) v[i] = sG[(blk*16+i)*33 + tid];
      #pragma unroll
      for (int i = 0; i < 16; ++i) { c0 += v[i]; sG[(blk*16+i)*33 + tid] = c0; }
    }
  }
  float knr[8];
  {
    const float* qp = qin + (((size_t)b*Tt + t0 + iq)*Hh + h)*32 + kq;
    float qr[8]; float ssq = 0.f;
    #pragma unroll
    for (int r = 0; r < 8; ++r) { qr[r] = qp[r]; ssq += qr[r]*qr[r]; }
    ssq += __shfl_xor(ssq, 1); ssq += __shfl_xor(ssq, 2);
    const float scq = 0.17677669529663687f / fmaxf(sqrtf(ssq), 1e-6f);
    #pragma unroll
    for (int r = 0; r < 8; ++r) sQ[iq*33 + kq + r] = qr[r]*scq;

    const float* kp = kin + (((size_t)b*Tt + t0 + iq)*Hh + h)*32 + kq;
    float ssk = 0.f;
    #pragma unroll
    for (int r = 0; r < 8; ++r) { knr[r] = kp[r]; ssk += knr[r]*knr[r]; }
    ssk += __shfl_xor(ssk, 1); ssk += __shfl_xor(ssk, 2);
    const float sck = 1.f / fmaxf(sqrtf(ssk), 1e-6f);
    #pragma unroll
    for (int r = 0; r < 8; ++r) knr[r] *= sck;
  }
  __syncthreads();

  float* P  = sV;
  float* Qb = sV + 2304;
  const int i64 = tid & 63, jj2 = (tid >> 6)*2;
  const int pL = i64 >> 4, pLb = pL*(pL+1)/2, iL = i64 & 15;
  for (int jt = 0; jt < 8; ++jt) {
    const int j0 = jt*8;
    {
      float pv[8];
      #pragma unroll
      for (int r = 0; r < 8; ++r) {
        const int idx = iq*33 + kq + r;
        pv[r] = sQ[idx] * __expf(fminf(sG[idx] - sG[j0*33 + kq + r], 0.f));
      }
      *(float4*)(P + iq*36 + kq)     = make_float4(pv[0],pv[1],pv[2],pv[3]);
      *(float4*)(P + iq*36 + kq + 4) = make_float4(pv[4],pv[5],pv[6],pv[7]);
    }
    if (iq >= j0 && iq < j0 + 8) {
      const int jj = iq - j0;
      #pragma unroll
      for (int r = 0; r < 8; ++r)
        Qb[jj*32 + kq + r] = knr[r] * __expf(sG[j0*33 + kq + r] - sG[iq*33 + kq + r]);
    }
    __syncthreads();
    float a0 = 0.f, a1 = 0.f;
    #pragma unroll
    for (int hf = 0; hf < 2; ++hf) {
      const int k0 = hf*16;
      #pragma unroll
      for (int t4 = 0; t4 < 4; ++t4) {
        const float4 pa = *(const float4*)(P  + i64*36 + k0 + t4*4);
        const float4 xa = *(const float4*)(Qb + (jj2  )*32 + k0 + t4*4);
        const float4 xb = *(const float4*)(Qb + (jj2+1)*32 + k0 + t4*4);
        a0 += pa.x*xa.x + pa.y*xa.y + pa.z*xa.z + pa.w*xa.w;
        a1 += pa.x*xb.x + pa.y*xb.y + pa.z*xb.z + pa.w*xb.w;
      }
    }
    const int j_0 = j0 + jj2;
    const int qB = j_0 >> 4;
    if (pL >= qB) {
      float* Ab = sA + (pLb + qB)*272 + iL*17;
      Ab[(j_0  ) & 15] = (i64 >= j_0  ) ? a0 : 0.f;   // inclusive diagonal
      Ab[(j_0+1) & 15] = (i64 >= j_0+1) ? a1 : 0.f;
    }
    __syncthreads();
  }

  float qgr[8];
  {
    #pragma unroll
    for (int r = 0; r < 8; ++r) {
      const int idx = iq*33 + kq + r;
      qgr[r] = sQ[idx] * __expf(sG[idx]);
    }
  }
  __syncthreads();   // gcum + P/Qb dead
  { // stage S into sG[0..2048) and w into sV[0..2048)
    #pragma unroll
    for (int rr = 0; rr < 2; ++rr) {
      const int f = tid + 256*rr;
      *(float4*)(sG + f*4) = *(const float4*)(wsS + (size_t)ch*2048 + f*4);
    }
    *(float4*)(sV + tid*8)     = *(const float4*)(wsW + (size_t)ch*2048 + tid*8);
    *(float4*)(sV + tid*8 + 4) = *(const float4*)(wsW + (size_t)ch*2048 + tid*8 + 4);
  }
  __syncthreads();
  const int pT = iq >> 4, pTb = pT*(pT+1)/2;
  const int r17 = (iq & 15)*17, iqm = iq & 15;
  { // qeff = qg - Aqk @ w  -> sQ
    float qe[8];
    #pragma unroll
    for (int r = 0; r < 8; ++r) qe[r] = qgr[r];
    for (int m = 0; m <= pT; ++m) {
      const float* Ab = sA + (pTb + m)*272 + r17;
      const int jmax = (m == pT) ? iqm : 15;
      const float* wb = sV + m*16*32 + kq;
      for (int jj = 0; jj <= jmax; ++jj) {
        const float av = Ab[jj];
        const float4 w0 = *(const float4*)(wb + jj*32);
        const float4 w1 = *(const float4*)(wb + jj*32 + 4);
        qe[0]-=av*w0.x; qe[1]-=av*w0.y; qe[2]-=av*w0.z; qe[3]-=av*w0.w;
        qe[4]-=av*w1.x; qe[5]-=av*w1.y; qe[6]-=av*w1.z; qe[7]-=av*w1.w;
      }
    }
    #pragma unroll
    for (int r = 0; r < 8; ++r) sQ[iq*33 + kq + r] = qe[r];
  }
  __syncthreads();   // qeff visible; w reads done

  const int vs8 = (tid & 3)*8;
  for (int vh = 0; vh < 2; ++vh) {
    { // stage u-half
      #pragma unroll
      for (int r = 0; r < 2; ++r) {
        const int f = tid + 256*r;
        const int j = f >> 3, ccu = (f & 7)*4;
        *(float4*)(sV + j*32 + ccu) = *(const float4*)(wsU + (size_t)ch*4096 + j*64 + vh*32 + ccu);
      }
    }
    __syncthreads();
    float acc[8];
    #pragma unroll
    for (int r = 0; r < 8; ++r) acc[r] = 0.f;
    { // qeff @ S (this col-half)
      for (int kk = 0; kk < 32; ++kk) {
        const float qv = sQ[iq*33 + kk];
        const float* sb = sG + kk*64 + vh*32 + vs8;
        const float4 s0 = *(const float4*)sb;
        const float4 s1 = *(const float4*)(sb + 4);
        acc[0]+=qv*s0.x; acc[1]+=qv*s0.y; acc[2]+=qv*s0.z; acc[3]+=qv*s0.w;
        acc[4]+=qv*s1.x; acc[5]+=qv*s1.y; acc[6]+=qv*s1.z; acc[7]+=qv*s1.w;
      }
    }
    { // Aqk @ u-half
      for (int m = 0; m <= pT; ++m) {
        const float* Ab = sA + (pTb + m)*272 + r17;
        const int jmax = (m == pT) ? iqm : 15;
        const float* ub = sV + m*16*32 + vs8;
        for (int jj = 0; jj <= jmax; ++jj) {
          const float av = Ab[jj];
          const float4 u0 = *(const float4*)(ub + jj*32);
          const float4 u1 = *(const float4*)(ub + jj*32 + 4);
          acc[0]+=av*u0.x; acc[1]+=av*u0.y; acc[2]+=av*u0.z; acc[3]+=av*u0.w;
          acc[4]+=av*u1.x; acc[5]+=av*u1.y; acc[6]+=av*u1.z; acc[7]+=av*u1.w;
        }
      }
    }
    float* op = out + (((size_t)b*Tt + t0 + iq)*Hh + h)*64 + vh*32 + vs8;
    *(float4*)(op)     = make_float4(acc[0],acc[1],acc[2],acc[3]);
    *(float4*)(op + 4) = make_float4(acc[4],acc[5],acc[6],acc[7]);
    __syncthreads();   // u reads done before next stage
  }
}

extern "C" void kernel_launch(void* const* d_in, const int* in_sizes, int n_in,
                              void* d_out, int out_size, void* d_ws, size_t ws_size,
                              hipStream_t stream) {
  const float* q    = (const float*)d_in[0];
  const float* k    = (const float*)d_in[1];
  const float* v    = (const float*)d_in[2];
  const float* graw = (const float*)d_in[3];
  const float* beta = (const float*)d_in[4];
  const float* A_log= (const float*)d_in[5];
  const float* dtb  = (const float*)d_in[6];
  float* out = (float*)d_out;
  float* ws  = (float*)d_ws;
  // requires ws_size >= 156.3 MB

  kda_phase1<<<NCH, 256, 0, stream>>>(k, v, graw, beta, A_log, dtb, ws);
  kda_scanA<<<1024, 256, 0, stream>>>(ws);
  kda_scanB<<<128, 256, 0, stream>>>(ws);
  kda_scanC<<<1024, 256, 0, stream>>>(ws);
  kda_phase3<<<NCH, 256, 0, stream>>>(q, k, graw, A_log, dtb, ws, out);
}

// Round 6
// 534.865 us; speedup vs baseline: 1.0809x; 1.0809x over previous
//
#include <hip/hip_runtime.h>
#include <math.h>

// Problem constants (B,T,H,K,V,BT) = (2,8192,16,32,64,64)
#define Tt 8192
#define Hh 16
#define NCH 4096        // chunk-heads, ch = c*32 + (b*16+h)
// Workspace layout (floats):
//   wsW  [NCH][2048]  w (64x32 row-major)
//   wsU  [NCH][4096]  u (64x64 row-major)
//   wsM  [NCH][1024]  M = diag(egl) - Kd^T W
//   wsC  [NCH][2048]  C = Kd^T U   -> overwritten by entering-S (32x64) in scanC
//   wsMs [256][1024]  per-segment composed M
//   wsCs [256][2048]  per-segment composed C
//   wsSs [256][2048]  entering S per segment

#define OFF_U   ((size_t)NCH*2048)
#define OFF_M   ((size_t)NCH*6144)
#define OFF_C   ((size_t)NCH*7168)
#define OFF_MS  ((size_t)NCH*9216)
#define OFF_CS  (OFF_MS + (size_t)256*1024)
#define OFF_SS  (OFF_CS + (size_t)256*2048)

__device__ __forceinline__ float softplusf(float x) {
  return fmaxf(x, 0.f) + log1pf(__expf(-fabsf(x)));
}

// blk(p,q) = p*(p+1)/2 + q for p>=q (10 blocks of a 4x4 block-triangle)

// ---------------- Phase 1 (R5-proven: 209us, LDS 40448, VGPR 56, 4 blk/CU) ----------------
__global__ __launch_bounds__(256) void kda_phase1(
    const float* __restrict__ kin, const float* __restrict__ vin,
    const float* __restrict__ graw, const float* __restrict__ beta,
    const float* __restrict__ A_log, const float* __restrict__ dt_bias,
    float* __restrict__ ws)
{
  __shared__ float sG[64*33];   // gcum (s33) -> w (s32, 2048)
  __shared__ float sK[64*33];   // kn -> kd (s33)
  __shared__ float sU[2720];    // P(2304,s36)+Qb(256 @2304) -> Tm-packed (10x272)
  __shared__ float sW[3104];    // L-packed(10x256) + sC2(2x272 @2560) -> k_egb(2048) -> vb/u-half(2048); Egl @3072

  const int tid = threadIdx.x;
  const int ch = blockIdx.x;
  const int c = ch >> 5, bh = ch & 31;
  const int b = bh >> 4, h = bh & 15;
  const int t0 = c*64;
  const int iq = tid >> 2, kq = (tid & 3)*8;

  float* wsW = ws;
  float* wsU = ws + OFF_U;
  float* wsM = ws + OFF_M;
  float* wsCc= ws + OFF_C;

  const float negA = -__expf(A_log[h]);

  { // gate g into sG
    const float* gr = graw + (((size_t)b*Tt + t0 + iq)*Hh + h)*32 + kq;
    const float* db = dt_bias + h*32 + kq;
    #pragma unroll
    for (int r = 0; r < 8; ++r)
      sG[iq*33 + kq + r] = negA * softplusf(gr[r] + db[r]);
  }
  __syncthreads();
  if (tid < 32) { // register-chunked cumsum over time per k
    float c0 = 0.f;
    for (int blk = 0; blk < 4; ++blk) {
      float v[16];
      #pragma unroll
      for (int i = 0; i < 16; ++i) v[i] = sG[(blk*16+i)*33 + tid];
      #pragma unroll
      for (int i = 0; i < 16; ++i) { c0 += v[i]; sG[(blk*16+i)*33 + tid] = c0; }
    }
  }
  { // k row-l2-normalize into sK
    const float* kp = kin + (((size_t)b*Tt + t0 + iq)*Hh + h)*32 + kq;
    float kr[8]; float ss = 0.f;
    #pragma unroll
    for (int r = 0; r < 8; ++r) { kr[r] = kp[r]; ss += kr[r]*kr[r]; }
    ss += __shfl_xor(ss, 1); ss += __shfl_xor(ss, 2);
    const float sc = 1.f / fmaxf(sqrtf(ss), 1e-6f);
    #pragma unroll
    for (int r = 0; r < 8; ++r) sK[iq*33 + kq + r] = kr[r]*sc;
  }
  __syncthreads();

  // ---- Akk tiles -> L packed ----
  const float b_cm = beta[((size_t)b*Tt + t0 + (tid & 63))*Hh + h];
  float* P  = sU;          // 64x36
  float* Qb = sU + 2304;   // 8x32
  const int i64 = tid & 63, jj2 = (tid >> 6)*2;
  const int pL = i64 >> 4, pLb = pL*(pL+1)/2, iL = i64 & 15;
  for (int jt = 0; jt < 8; ++jt) {
    const int j0 = jt*8;
    {
      float pv[8];
      #pragma unroll
      for (int r = 0; r < 8; ++r) {
        const int idx = iq*33 + kq + r;
        pv[r] = sK[idx] * __expf(fminf(sG[idx] - sG[j0*33 + kq + r], 0.f));
      }
      *(float4*)(P + iq*36 + kq)     = make_float4(pv[0],pv[1],pv[2],pv[3]);
      *(float4*)(P + iq*36 + kq + 4) = make_float4(pv[4],pv[5],pv[6],pv[7]);
    }
    {
      const int jj = tid >> 5, kk = tid & 31;
      Qb[jj*32 + kk] = sK[(j0+jj)*33 + kk] * __expf(sG[j0*33 + kk] - sG[(j0+jj)*33 + kk]);
    }
    __syncthreads();
    float a0 = 0.f, a1 = 0.f;
    #pragma unroll
    for (int hf = 0; hf < 2; ++hf) {
      const int k0 = hf*16;
      #pragma unroll
      for (int t4 = 0; t4 < 4; ++t4) {
        const float4 pa = *(const float4*)(P  + i64*36 + k0 + t4*4);
        const float4 xa = *(const float4*)(Qb + (jj2  )*32 + k0 + t4*4);
        const float4 xb = *(const float4*)(Qb + (jj2+1)*32 + k0 + t4*4);
        a0 += pa.x*xa.x + pa.y*xa.y + pa.z*xa.z + pa.w*xa.w;
        a1 += pa.x*xb.x + pa.y*xb.y + pa.z*xb.z + pa.w*xb.w;
      }
    }
    const int j_0 = j0 + jj2;
    const int qB = j_0 >> 4;
    if (pL >= qB) {   // only lower blocks stored
      float* Lb = sW + (pLb + qB)*256 + iL;
      Lb[((j_0  ) & 15)*16] = (i64 > j_0  ) ? a0*b_cm : 0.f;
      Lb[((j_0+1) & 15)*16] = (i64 > j_0+1) ? a1*b_cm : 0.f;
    }
    __syncthreads();
  }

  // ---- Tm = (I+L)^-1: diag blocks ----
  if (tid < 64) {
    const int p = tid >> 4, col = tid & 15;
    const int bD = p*(p+1)/2 + p;
    float* Td = sU + bD*272;
    const float* Ld = sW + bD*256;
    Td[col] = (col == 0) ? 1.f : 0.f;   // row 0
    for (int i = 1; i < 16; ++i) {
      float acc = 0.f;
      for (int j = 0; j < i; ++j)
        acc -= Ld[j*16 + i] * Td[j*17 + col];
      Td[i*17 + col] = acc + ((i == col) ? 1.f : 0.f);
    }
  }
  __syncthreads();
  // off-diagonal: 2 waves x 3 rounds
  {
    const int wid = tid >> 6;
    const int lane = tid & 63;
    const int ri = lane & 15, c4 = (lane >> 4)*4;
    float* Ct = sW + 2560 + wid*272;
    auto offblk = [&](int p, int q) {
      const int pb = p*(p+1)/2;
      float a0=0.f, a1=0.f, a2=0.f, a3=0.f;
      for (int m = q; m < p; ++m) {
        const float* Lb = sW + (pb + m)*256;
        const float* Tb = sU + (m*(m+1)/2 + q)*272;
        #pragma unroll
        for (int j = 0; j < 16; ++j) {
          const float lv = Lb[j*16 + ri];
          const float* tp = Tb + j*17 + c4;
          a0 += lv*tp[0]; a1 += lv*tp[1]; a2 += lv*tp[2]; a3 += lv*tp[3];
        }
      }
      float* cp = Ct + ri*17 + c4;
      cp[0]=a0; cp[1]=a1; cp[2]=a2; cp[3]=a3;
      const float* Tpp = sU + (pb + p)*272 + ri*17;
      float b0=0.f, b1=0.f, b2=0.f, b3=0.f;
      #pragma unroll
      for (int j = 0; j < 16; ++j) {
        const float tv = Tpp[j];
        const float* cj = Ct + j*17 + c4;
        b0 += tv*cj[0]; b1 += tv*cj[1]; b2 += tv*cj[2]; b3 += tv*cj[3];
      }
      float* op = sU + (pb + q)*272 + ri*17 + c4;
      op[0]=-b0; op[1]=-b1; op[2]=-b2; op[3]=-b3;
    };
    if (wid == 0) offblk(1,0); else if (wid == 1) offblk(2,1);
    __syncthreads();
    if (wid == 0) offblk(2,0); else if (wid == 1) offblk(3,1);
    __syncthreads();
    if (wid == 0) offblk(3,0); else if (wid == 1) offblk(3,2);
  }
  __syncthreads();

  { // k_egb into sW[0..2048); kd -> sK; Egl @ sW+3072
    const float b_row = beta[((size_t)b*Tt + t0 + iq)*Hh + h];
    #pragma unroll
    for (int r = 0; r < 8; ++r) {
      const int idx = iq*33 + kq + r;
      const float g = sG[idx], kn = sK[idx];
      sW[iq*32 + kq + r] = b_row * kn * __expf(g);
      sK[idx] = kn * __expf(sG[63*33 + kq + r] - g);
    }
    if (tid < 32) sW[3072 + tid] = __expf(sG[63*33 + tid]);
  }
  __syncthreads();

  const int pT = iq >> 4, pTb = pT*(pT+1)/2;
  const int r17 = (iq & 15)*17, iqm = iq & 15;

  { // w = Tm @ k_egb -> global + sG (gcum dead)
    float acc[8] = {0,0,0,0,0,0,0,0};
    for (int m = 0; m <= pT; ++m) {
      const float* Tb = sU + (pTb + m)*272 + r17;
      const int jmax = (m == pT) ? iqm : 15;
      const float* eb = sW + m*16*32 + kq;
      for (int jj = 0; jj <= jmax; ++jj) {
        const float t = Tb[jj];
        const float4 e0 = *(const float4*)(eb + jj*32);
        const float4 e1 = *(const float4*)(eb + jj*32 + 4);
        acc[0]+=t*e0.x; acc[1]+=t*e0.y; acc[2]+=t*e0.z; acc[3]+=t*e0.w;
        acc[4]+=t*e1.x; acc[5]+=t*e1.y; acc[6]+=t*e1.z; acc[7]+=t*e1.w;
      }
    }
    #pragma unroll
    for (int r = 0; r < 8; ++r) {
      wsW[(size_t)ch*2048 + tid*8 + r] = acc[r];
      sG[iq*32 + kq + r] = acc[r];
    }
  }
  __syncthreads();   // k_egb reads done; w visible

  const int vs8 = (tid & 3)*8;
  for (int vh = 0; vh < 2; ++vh) {
    { // stage vb-half (64 x 32 cols)
      #pragma unroll
      for (int r = 0; r < 2; ++r) {
        const int f = tid + 256*r;
        const int j = f >> 3, cc = (f & 7)*4;
        const float bj = beta[((size_t)b*Tt + t0 + j)*Hh + h];
        float4 v4 = *(const float4*)(vin + (((size_t)b*Tt + t0 + j)*Hh + h)*64 + vh*32 + cc);
        v4.x *= bj; v4.y *= bj; v4.z *= bj; v4.w *= bj;
        *(float4*)(sW + j*32 + cc) = v4;
      }
    }
    __syncthreads();
    float ua[8];
    { // u-half = Tm @ vb-half -> wsU
      #pragma unroll
      for (int r = 0; r < 8; ++r) ua[r] = 0.f;
      for (int m = 0; m <= pT; ++m) {
        const float* Tb = sU + (pTb + m)*272 + r17;
        const int jmax = (m == pT) ? iqm : 15;
        const float* eb = sW + m*16*32 + vs8;
        for (int jj = 0; jj <= jmax; ++jj) {
          const float t = Tb[jj];
          const float4 e0 = *(const float4*)(eb + jj*32);
          const float4 e1 = *(const float4*)(eb + jj*32 + 4);
          ua[0]+=t*e0.x; ua[1]+=t*e0.y; ua[2]+=t*e0.z; ua[3]+=t*e0.w;
          ua[4]+=t*e1.x; ua[5]+=t*e1.y; ua[6]+=t*e1.z; ua[7]+=t*e1.w;
        }
      }
      *(float4*)(wsU + (size_t)ch*4096 + iq*64 + vh*32 + vs8)     = make_float4(ua[0],ua[1],ua[2],ua[3]);
      *(float4*)(wsU + (size_t)ch*4096 + iq*64 + vh*32 + vs8 + 4) = make_float4(ua[4],ua[5],ua[6],ua[7]);
    }
    __syncthreads();   // all vb reads done
    *(float4*)(sW + iq*32 + vs8)     = make_float4(ua[0],ua[1],ua[2],ua[3]);
    *(float4*)(sW + iq*32 + vs8 + 4) = make_float4(ua[4],ua[5],ua[6],ua[7]);
    __syncthreads();
    if (vh == 0) { // M = diag(egl) - Kd^T W (once)
      const int a = tid >> 3, b4 = (tid & 7)*4;
      float mA[4] = {0.f,0.f,0.f,0.f};
      for (int t = 0; t < 64; ++t) {
        const float kd = sK[t*33 + a];
        const float4 wv = *(const float4*)(sG + t*32 + b4);
        mA[0]+=kd*wv.x; mA[1]+=kd*wv.y; mA[2]+=kd*wv.z; mA[3]+=kd*wv.w;
      }
      const float eg = sW[3072 + a];
      float4 m4;
      m4.x = ((a == b4+0) ? eg : 0.f) - mA[0];
      m4.y = ((a == b4+1) ? eg : 0.f) - mA[1];
      m4.z = ((a == b4+2) ? eg : 0.f) - mA[2];
      m4.w = ((a == b4+3) ? eg : 0.f) - mA[3];
      *(float4*)(wsM + (size_t)ch*1024 + tid*4) = m4;
    }
    { // C-half = Kd^T U-half
      const int a = tid >> 3, c4c = (tid & 7)*4;
      float cA[4] = {0.f,0.f,0.f,0.f};
      for (int t = 0; t < 64; ++t) {
        const float kd = sK[t*33 + a];
        const float4 u4 = *(const float4*)(sW + t*32 + c4c);
        cA[0]+=kd*u4.x; cA[1]+=kd*u4.y; cA[2]+=kd*u4.z; cA[3]+=kd*u4.w;
      }
      *(float4*)(wsCc + (size_t)ch*2048 + a*64 + vh*32 + c4c) = make_float4(cA[0],cA[1],cA[2],cA[3]);
    }
    __syncthreads();   // C reads done before next stage
  }
}

// ---------------- scanA ----------------
__global__ __launch_bounds__(256) void kda_scanA(float* __restrict__ ws)
{
  __shared__ float sMa[32*33];
  __shared__ float sMc[32*33];
  __shared__ float sCa[32*18];
  const int tid = threadIdx.x;
  const int vt = blockIdx.x & 3, seg = (blockIdx.x >> 2) & 7, bh = blockIdx.x >> 5;
  const int v0 = vt*16;
  const int a = tid >> 3, b4 = (tid & 7)*4, c2 = (tid & 7)*2;
  const float* wsM = ws + OFF_M;
  const float* wsC = ws + OFF_C;

  #pragma unroll
  for (int r = 0; r < 4; ++r) sMa[a*33 + b4 + r] = (a == b4 + r) ? 1.f : 0.f;
  sCa[a*18 + c2] = 0.f; sCa[a*18 + c2 + 1] = 0.f;

  int ch = (seg*16)*32 + bh;
  float4 m4 = *(const float4*)(wsM + (size_t)ch*1024 + tid*4);
  float2 cc = *(const float2*)(wsC + (size_t)ch*2048 + a*64 + v0 + c2);

  for (int i = 0; i < 16; ++i) {
    sMc[a*33+b4+0]=m4.x; sMc[a*33+b4+1]=m4.y; sMc[a*33+b4+2]=m4.z; sMc[a*33+b4+3]=m4.w;
    __syncthreads();
    float4 m4n = m4; float2 ccn = cc;
    if (i < 15) {
      const int chn = (seg*16 + i + 1)*32 + bh;
      m4n = *(const float4*)(wsM + (size_t)chn*1024 + tid*4);
      ccn = *(const float2*)(wsC + (size_t)chn*2048 + a*64 + v0 + c2);
    }
    float cn0 = cc.x, cn1 = cc.y;
    float mn0=0.f, mn1=0.f, mn2=0.f, mn3=0.f;
    for (int bb = 0; bb < 32; ++bb) {
      const float m = sMc[a*33 + bb];
      const float2 s2 = *(const float2*)(sCa + bb*18 + c2);
      cn0 += m*s2.x; cn1 += m*s2.y;
      mn0 += m*sMa[bb*33+b4+0]; mn1 += m*sMa[bb*33+b4+1];
      mn2 += m*sMa[bb*33+b4+2]; mn3 += m*sMa[bb*33+b4+3];
    }
    __syncthreads();
    sCa[a*18+c2] = cn0; sCa[a*18+c2+1] = cn1;
    sMa[a*33+b4+0]=mn0; sMa[a*33+b4+1]=mn1; sMa[a*33+b4+2]=mn2; sMa[a*33+b4+3]=mn3;
    m4 = m4n; cc = ccn;
  }
  const size_t sid = (size_t)(bh*8 + seg);
  float* wsMs = ws + OFF_MS;
  float* wsCs = ws + OFF_CS;
  if (vt == 0) {
    #pragma unroll
    for (int r = 0; r < 4; ++r) wsMs[sid*1024 + tid*4 + r] = sMa[a*33+b4+r];
  }
  float2 co; co.x = sCa[a*18+c2]; co.y = sCa[a*18+c2+1];
  *(float2*)(wsCs + sid*2048 + a*64 + v0 + c2) = co;
}

// ---------------- scanB ----------------
__global__ __launch_bounds__(256) void kda_scanB(float* __restrict__ ws)
{
  __shared__ float sS[32*18];
  __shared__ float sM[32*33];
  const int tid = threadIdx.x;
  const int vt = blockIdx.x & 3, bh = blockIdx.x >> 2;
  const int v0 = vt*16;
  const int a = tid >> 3, b4 = (tid & 7)*4, c2 = (tid & 7)*2;
  const float* wsMs = ws + OFF_MS;
  const float* wsCs = ws + OFF_CS;
  float* wsSs = ws + OFF_SS;

  float s0 = 0.f, s1 = 0.f;
  sS[a*18 + c2] = 0.f; sS[a*18 + c2 + 1] = 0.f;
  const size_t sid0 = (size_t)(bh*8);
  float4 m4 = *(const float4*)(wsMs + sid0*1024 + tid*4);
  float2 cc = *(const float2*)(wsCs + sid0*2048 + a*64 + v0 + c2);

  for (int seg = 0; seg < 8; ++seg) {
    const size_t sid = (size_t)(bh*8 + seg);
    *(float2*)(wsSs + sid*2048 + a*64 + v0 + c2) = make_float2(s0, s1);
    sM[a*33+b4+0]=m4.x; sM[a*33+b4+1]=m4.y; sM[a*33+b4+2]=m4.z; sM[a*33+b4+3]=m4.w;
    __syncthreads();
    float4 m4n = m4; float2 ccn = cc;
    if (seg < 7) {
      m4n = *(const float4*)(wsMs + (sid+1)*1024 + tid*4);
      ccn = *(const float2*)(wsCs + (sid+1)*2048 + a*64 + v0 + c2);
    }
    float n0 = cc.x, n1 = cc.y;
    for (int bb = 0; bb < 32; ++bb) {
      const float m = sM[a*33 + bb];
      const float2 s2 = *(const float2*)(sS + bb*18 + c2);
      n0 += m*s2.x; n1 += m*s2.y;
    }
    __syncthreads();
    s0 = n0; s1 = n1;
    sS[a*18+c2] = s0; sS[a*18+c2+1] = s1;
    m4 = m4n; cc = ccn;
  }
}

// ---------------- scanC ----------------
__global__ __launch_bounds__(256) void kda_scanC(float* __restrict__ ws)
{
  __shared__ float sM[32*33];
  __shared__ float sS[32*18];
  const int tid = threadIdx.x;
  const int vt = blockIdx.x & 3, seg = (blockIdx.x >> 2) & 7, bh = blockIdx.x >> 5;
  const int v0 = vt*16;
  const int a = tid >> 3, b4 = (tid & 7)*4, c2 = (tid & 7)*2;
  const float* wsM = ws + OFF_M;
  float* wsC = ws + OFF_C;
  const float* wsSs = ws + OFF_SS;

  const size_t sid = (size_t)(bh*8 + seg);
  float s0, s1;
  {
    float2 sv = *(const float2*)(wsSs + sid*2048 + a*64 + v0 + c2);
    s0 = sv.x; s1 = sv.y;
    sS[a*18 + c2] = s0; sS[a*18 + c2 + 1] = s1;
  }
  int ch = (seg*16)*32 + bh;
  float4 m4 = *(const float4*)(wsM + (size_t)ch*1024 + tid*4);
  float2 cc = *(const float2*)(wsC + (size_t)ch*2048 + a*64 + v0 + c2);

  for (int i = 0; i < 16; ++i) {
    const int chc = (seg*16 + i)*32 + bh;
    sM[a*33+b4+0]=m4.x; sM[a*33+b4+1]=m4.y; sM[a*33+b4+2]=m4.z; sM[a*33+b4+3]=m4.w;
    *(float2*)(wsC + (size_t)chc*2048 + a*64 + v0 + c2) = make_float2(s0, s1);
    __syncthreads();
    float4 m4n = m4; float2 ccn = cc;
    if (i < 15) {
      const int chn = (seg*16 + i + 1)*32 + bh;
      m4n = *(const float4*)(wsM + (size_t)chn*1024 + tid*4);
      ccn = *(const float2*)(wsC + (size_t)chn*2048 + a*64 + v0 + c2);
    }
    float n0 = cc.x, n1 = cc.y;
    for (int bb = 0; bb < 32; ++bb) {
      const float m = sM[a*33 + bb];
      const float2 s2 = *(const float2*)(sS + bb*18 + c2);
      n0 += m*s2.x; n1 += m*s2.y;
    }
    __syncthreads();
    s0 = n0; s1 = n1;
    sS[a*18+c2] = s0; sS[a*18+c2+1] = s1;
    m4 = m4n; cc = ccn;
  }
}

// ---------------- Phase 3 ----------------
// Aqk packed 10x272; LDS 38.0KB => 4 blocks/CU.
// o-phase: u staged in two ROW-halves (dense 8KB copies), single acc[16],
// triangular Aqk loop partitioned by row-block -- fixes R5's column-split
// regression (half-dense staging + doubled loop overhead + halved ILP).
__global__ __launch_bounds__(256) void kda_phase3(
    const float* __restrict__ qin, const float* __restrict__ kin,
    const float* __restrict__ graw,
    const float* __restrict__ A_log, const float* __restrict__ dt_bias,
    const float* __restrict__ ws, float* __restrict__ out)
{
  __shared__ float sG[64*33];   // gcum (s33) -> S (32x64, 2048)
  __shared__ float sQ[64*33];   // qn -> qeff
  __shared__ float sA[2720];    // Aqk packed (10x272)
  __shared__ float sV[2560];    // P(2304,s36)+Qb(@2304) -> w(2048) -> u-row-half(2048)

  const int tid = threadIdx.x;
  const int ch = blockIdx.x;
  const int c = ch >> 5, bh = ch & 31;
  const int b = bh >> 4, h = bh & 15;
  const int t0 = c*64;
  const int iq = tid >> 2, kq = (tid & 3)*8;

  const float* wsW = ws;            // w (64x32)
  const float* wsU = ws + OFF_U;    // u (64x64)
  const float* wsS = ws + OFF_C;    // entering S (32x64)

  const float negA = -__expf(A_log[h]);
  {
    const float* gr = graw + (((size_t)b*Tt + t0 + iq)*Hh + h)*32 + kq;
    const float* db = dt_bias + h*32 + kq;
    #pragma unroll
    for (int r = 0; r < 8; ++r)
      sG[iq*33 + kq + r] = negA * softplusf(gr[r] + db[r]);
  }
  __syncthreads();
  if (tid < 32) {
    float c0 = 0.f;
    for (int blk = 0; blk < 4; ++blk) {
      float v[16];
      #pragma unroll
      for (int i = 0; i < 16; ++i) v[i] = sG[(blk*16+i)*33 + tid];
      #pragma unroll
      for (int i = 0; i < 16; ++i) { c0 += v[i]; sG[(blk*16+i)*33 + tid] = c0; }
    }
  }
  float knr[8];
  {
    const float* qp = qin + (((size_t)b*Tt + t0 + iq)*Hh + h)*32 + kq;
    float qr[8]; float ssq = 0.f;
    #pragma unroll
    for (int r = 0; r < 8; ++r) { qr[r] = qp[r]; ssq += qr[r]*qr[r]; }
    ssq += __shfl_xor(ssq, 1); ssq += __shfl_xor(ssq, 2);
    const float scq = 0.17677669529663687f / fmaxf(sqrtf(ssq), 1e-6f);
    #pragma unroll
    for (int r = 0; r < 8; ++r) sQ[iq*33 + kq + r] = qr[r]*scq;

    const float* kp = kin + (((size_t)b*Tt + t0 + iq)*Hh + h)*32 + kq;
    float ssk = 0.f;
    #pragma unroll
    for (int r = 0; r < 8; ++r) { knr[r] = kp[r]; ssk += knr[r]*knr[r]; }
    ssk += __shfl_xor(ssk, 1); ssk += __shfl_xor(ssk, 2);
    const float sck = 1.f / fmaxf(sqrtf(ssk), 1e-6f);
    #pragma unroll
    for (int r = 0; r < 8; ++r) knr[r] *= sck;
  }
  __syncthreads();

  float* P  = sV;
  float* Qb = sV + 2304;
  const int i64 = tid & 63, jj2 = (tid >> 6)*2;
  const int pL = i64 >> 4, pLb = pL*(pL+1)/2, iL = i64 & 15;
  for (int jt = 0; jt < 8; ++jt) {
    const int j0 = jt*8;
    {
      float pv[8];
      #pragma unroll
      for (int r = 0; r < 8; ++r) {
        const int idx = iq*33 + kq + r;
        pv[r] = sQ[idx] * __expf(fminf(sG[idx] - sG[j0*33 + kq + r], 0.f));
      }
      *(float4*)(P + iq*36 + kq)     = make_float4(pv[0],pv[1],pv[2],pv[3]);
      *(float4*)(P + iq*36 + kq + 4) = make_float4(pv[4],pv[5],pv[6],pv[7]);
    }
    if (iq >= j0 && iq < j0 + 8) {
      const int jj = iq - j0;
      #pragma unroll
      for (int r = 0; r < 8; ++r)
        Qb[jj*32 + kq + r] = knr[r] * __expf(sG[j0*33 + kq + r] - sG[iq*33 + kq + r]);
    }
    __syncthreads();
    float a0 = 0.f, a1 = 0.f;
    #pragma unroll
    for (int hf = 0; hf < 2; ++hf) {
      const int k0 = hf*16;
      #pragma unroll
      for (int t4 = 0; t4 < 4; ++t4) {
        const float4 pa = *(const float4*)(P  + i64*36 + k0 + t4*4);
        const float4 xa = *(const float4*)(Qb + (jj2  )*32 + k0 + t4*4);
        const float4 xb = *(const float4*)(Qb + (jj2+1)*32 + k0 + t4*4);
        a0 += pa.x*xa.x + pa.y*xa.y + pa.z*xa.z + pa.w*xa.w;
        a1 += pa.x*xb.x + pa.y*xb.y + pa.z*xb.z + pa.w*xb.w;
      }
    }
    const int j_0 = j0 + jj2;
    const int qB = j_0 >> 4;
    if (pL >= qB) {
      float* Ab = sA + (pLb + qB)*272 + iL*17;
      Ab[(j_0  ) & 15] = (i64 >= j_0  ) ? a0 : 0.f;   // inclusive diagonal
      Ab[(j_0+1) & 15] = (i64 >= j_0+1) ? a1 : 0.f;
    }
    __syncthreads();
  }

  float qgr[8];
  {
    #pragma unroll
    for (int r = 0; r < 8; ++r) {
      const int idx = iq*33 + kq + r;
      qgr[r] = sQ[idx] * __expf(sG[idx]);
    }
  }
  __syncthreads();   // gcum + P/Qb dead
  { // stage S into sG[0..2048) and w into sV[0..2048)
    #pragma unroll
    for (int rr = 0; rr < 2; ++rr) {
      const int f = tid + 256*rr;
      *(float4*)(sG + f*4) = *(const float4*)(wsS + (size_t)ch*2048 + f*4);
    }
    *(float4*)(sV + tid*8)     = *(const float4*)(wsW + (size_t)ch*2048 + tid*8);
    *(float4*)(sV + tid*8 + 4) = *(const float4*)(wsW + (size_t)ch*2048 + tid*8 + 4);
  }
  __syncthreads();
  const int pT = iq >> 4, pTb = pT*(pT+1)/2;
  const int r17 = (iq & 15)*17, iqm = iq & 15;
  { // qeff = qg - Aqk @ w  -> sQ
    float qe[8];
    #pragma unroll
    for (int r = 0; r < 8; ++r) qe[r] = qgr[r];
    for (int m = 0; m <= pT; ++m) {
      const float* Ab = sA + (pTb + m)*272 + r17;
      const int jmax = (m == pT) ? iqm : 15;
      const float* wb = sV + m*16*32 + kq;
      for (int jj = 0; jj <= jmax; ++jj) {
        const float av = Ab[jj];
        const float4 w0 = *(const float4*)(wb + jj*32);
        const float4 w1 = *(const float4*)(wb + jj*32 + 4);
        qe[0]-=av*w0.x; qe[1]-=av*w0.y; qe[2]-=av*w0.z; qe[3]-=av*w0.w;
        qe[4]-=av*w1.x; qe[5]-=av*w1.y; qe[6]-=av*w1.z; qe[7]-=av*w1.w;
      }
    }
    #pragma unroll
    for (int r = 0; r < 8; ++r) sQ[iq*33 + kq + r] = qe[r];
  }
  __syncthreads();   // qeff visible; w reads done

  { // o = qeff @ S + Aqk @ u, u staged in two row-halves (dense copies)
    const int vs = (tid & 3)*16;
    float acc[16];
    #pragma unroll
    for (int r = 0; r < 16; ++r) acc[r] = 0.f;
    for (int vh = 0; vh < 2; ++vh) {
      { // stage u rows [vh*32, vh*32+32): contiguous 8KB
        #pragma unroll
        for (int rr = 0; rr < 2; ++rr) {
          const int f = tid + 256*rr;
          *(float4*)(sV + f*4) = *(const float4*)(wsU + (size_t)ch*4096 + vh*2048 + f*4);
        }
      }
      __syncthreads();
      if (vh == 0) { // qeff @ S (once; independent of u)
        for (int kk = 0; kk < 32; ++kk) {
          const float qv = sQ[iq*33 + kk];
          const float4 s0 = *(const float4*)(sG + kk*64 + vs);
          const float4 s1 = *(const float4*)(sG + kk*64 + vs + 4);
          const float4 s2 = *(const float4*)(sG + kk*64 + vs + 8);
          const float4 s3 = *(const float4*)(sG + kk*64 + vs + 12);
          acc[0]+=qv*s0.x;  acc[1]+=qv*s0.y;  acc[2]+=qv*s0.z;  acc[3]+=qv*s0.w;
          acc[4]+=qv*s1.x;  acc[5]+=qv*s1.y;  acc[6]+=qv*s1.z;  acc[7]+=qv*s1.w;
          acc[8]+=qv*s2.x;  acc[9]+=qv*s2.y;  acc[10]+=qv*s2.z; acc[11]+=qv*s2.w;
          acc[12]+=qv*s3.x; acc[13]+=qv*s3.y; acc[14]+=qv*s3.z; acc[15]+=qv*s3.w;
        }
      }
      // Aqk @ u rows in this half: blocks m = vh*2, vh*2+1 (clipped to pT)
      for (int m = vh*2; m <= pT && m < vh*2 + 2; ++m) {
        const float* Ab = sA + (pTb + m)*272 + r17;
        const int jmax = (m == pT) ? iqm : 15;
        const float* ub = sV + (m - vh*2)*16*64 + vs;
        for (int jj = 0; jj <= jmax; ++jj) {
          const float av = Ab[jj];
          const float4 u0 = *(const float4*)(ub + jj*64);
          const float4 u1 = *(const float4*)(ub + jj*64 + 4);
          const float4 u2 = *(const float4*)(ub + jj*64 + 8);
          const float4 u3 = *(const float4*)(ub + jj*64 + 12);
          acc[0]+=av*u0.x;  acc[1]+=av*u0.y;  acc[2]+=av*u0.z;  acc[3]+=av*u0.w;
          acc[4]+=av*u1.x;  acc[5]+=av*u1.y;  acc[6]+=av*u1.z;  acc[7]+=av*u1.w;
          acc[8]+=av*u2.x;  acc[9]+=av*u2.y;  acc[10]+=av*u2.z; acc[11]+=av*u2.w;
          acc[12]+=av*u3.x; acc[13]+=av*u3.y; acc[14]+=av*u3.z; acc[15]+=av*u3.w;
        }
      }
      if (vh == 0) __syncthreads();   // u reads done before restage
    }
    float* op = out + (((size_t)b*Tt + t0 + iq)*Hh + h)*64 + vs;
    #pragma unroll
    for (int rr = 0; rr < 4; ++rr) {
      float4 o4; o4.x=acc[rr*4]; o4.y=acc[rr*4+1]; o4.z=acc[rr*4+2]; o4.w=acc[rr*4+3];
      *(float4*)(op + rr*4) = o4;
    }
  }
}

extern "C" void kernel_launch(void* const* d_in, const int* in_sizes, int n_in,
                              void* d_out, int out_size, void* d_ws, size_t ws_size,
                              hipStream_t stream) {
  const float* q    = (const float*)d_in[0];
  const float* k    = (const float*)d_in[1];
  const float* v    = (const float*)d_in[2];
  const float* graw = (const float*)d_in[3];
  const float* beta = (const float*)d_in[4];
  const float* A_log= (const float*)d_in[5];
  const float* dtb  = (const float*)d_in[6];
  float* out = (float*)d_out;
  float* ws  = (float*)d_ws;
  // requires ws_size >= 156.3 MB

  kda_phase1<<<NCH, 256, 0, stream>>>(k, v, graw, beta, A_log, dtb, ws);
  kda_scanA<<<1024, 256, 0, stream>>>(ws);
  kda_scanB<<<128, 256, 0, stream>>>(ws);
  kda_scanC<<<1024, 256, 0, stream>>>(ws);
  kda_phase3<<<NCH, 256, 0, stream>>>(q, k, graw, A_log, dtb, ws, out);
}

// Round 7
// 523.888 us; speedup vs baseline: 1.1036x; 1.0210x over previous
//
#include <hip/hip_runtime.h>
#include <math.h>

// Problem constants (B,T,H,K,V,BT) = (2,8192,16,32,64,64)
#define Tt 8192
#define Hh 16
#define NCH 4096        // chunk-heads, ch = c*32 + (b*16+h)
// Workspace layout (floats):
//   wsW  [NCH][2048]  w (64x32 row-major)
//   wsU  [NCH][4096]  u (64x64 row-major)
//   wsM  [NCH][1024]  M = diag(egl) - Kd^T W
//   wsC  [NCH][2048]  C = Kd^T U   -> overwritten by entering-S (32x64) in scanC
//   wsMs [256][1024]  per-segment composed M
//   wsCs [256][2048]  per-segment composed C
//   wsSs [256][2048]  entering S per segment

#define OFF_U   ((size_t)NCH*2048)
#define OFF_M   ((size_t)NCH*6144)
#define OFF_C   ((size_t)NCH*7168)
#define OFF_MS  ((size_t)NCH*9216)
#define OFF_CS  (OFF_MS + (size_t)256*1024)
#define OFF_SS  (OFF_CS + (size_t)256*2048)

__device__ __forceinline__ float softplusf(float x) {
  return fmaxf(x, 0.f) + log1pf(__expf(-fabsf(x)));
}

// blk(p,q) = p*(p+1)/2 + q for p>=q (10 blocks of a 4x4 block-triangle)

// ---------------- Phase 1 ----------------
// 256 threads, LDS ~40.6KB => 4 blocks/CU. Akk now in 16-col tiles (4 tiles,
// 8 barriers vs 16; P exp/write/read traffic halved). 16-step cross-tile
// exponent empirically safe (R1-R3 passed with identical absmax).
__global__ __launch_bounds__(256) void kda_phase1(
    const float* __restrict__ kin, const float* __restrict__ vin,
    const float* __restrict__ graw, const float* __restrict__ beta,
    const float* __restrict__ A_log, const float* __restrict__ dt_bias,
    float* __restrict__ ws)
{
  __shared__ float sG[64*33];   // gcum (s33) -> w (s32, 2048)
  __shared__ float sK[64*33];   // kn -> kd (s33)
  __shared__ float sU[2816];    // P(2304,s36)+Qb(16x32 @2304) -> Tm-packed (10x272)
  __shared__ float sW[3104];    // L-packed(10x256) + sC2(2x272 @2560) -> k_egb(2048) -> vb/u-half(2048); Egl @3072

  const int tid = threadIdx.x;
  const int ch = blockIdx.x;
  const int c = ch >> 5, bh = ch & 31;
  const int b = bh >> 4, h = bh & 15;
  const int t0 = c*64;
  const int iq = tid >> 2, kq = (tid & 3)*8;

  float* wsW = ws;
  float* wsU = ws + OFF_U;
  float* wsM = ws + OFF_M;
  float* wsCc= ws + OFF_C;

  const float negA = -__expf(A_log[h]);

  { // gate g into sG
    const float* gr = graw + (((size_t)b*Tt + t0 + iq)*Hh + h)*32 + kq;
    const float* db = dt_bias + h*32 + kq;
    #pragma unroll
    for (int r = 0; r < 8; ++r)
      sG[iq*33 + kq + r] = negA * softplusf(gr[r] + db[r]);
  }
  __syncthreads();
  if (tid < 32) { // register-chunked cumsum over time per k
    float c0 = 0.f;
    for (int blk = 0; blk < 4; ++blk) {
      float v[16];
      #pragma unroll
      for (int i = 0; i < 16; ++i) v[i] = sG[(blk*16+i)*33 + tid];
      #pragma unroll
      for (int i = 0; i < 16; ++i) { c0 += v[i]; sG[(blk*16+i)*33 + tid] = c0; }
    }
  }
  { // k row-l2-normalize into sK
    const float* kp = kin + (((size_t)b*Tt + t0 + iq)*Hh + h)*32 + kq;
    float kr[8]; float ss = 0.f;
    #pragma unroll
    for (int r = 0; r < 8; ++r) { kr[r] = kp[r]; ss += kr[r]*kr[r]; }
    ss += __shfl_xor(ss, 1); ss += __shfl_xor(ss, 2);
    const float sc = 1.f / fmaxf(sqrtf(ss), 1e-6f);
    #pragma unroll
    for (int r = 0; r < 8; ++r) sK[iq*33 + kq + r] = kr[r]*sc;
  }
  __syncthreads();

  // ---- Akk in 16-col tiles (4 tiles, 8 barriers) -> L packed ----
  const float b_cm = beta[((size_t)b*Tt + t0 + (tid & 63))*Hh + h];
  float* P  = sU;          // 64x36
  float* Qb = sU + 2304;   // 16x32
  const int i64 = tid & 63;
  const int w4 = (tid >> 6)*2;          // wave col base: 0,2,4,6
  const int pL = i64 >> 4, pLb = pL*(pL+1)/2, iL = i64 & 15;
  for (int jt = 0; jt < 4; ++jt) {
    const int j0 = jt*16;
    {
      float pv[8];
      #pragma unroll
      for (int r = 0; r < 8; ++r) {
        const int idx = iq*33 + kq + r;
        pv[r] = sK[idx] * __expf(fminf(sG[idx] - sG[j0*33 + kq + r], 0.f));
      }
      *(float4*)(P + iq*36 + kq)     = make_float4(pv[0],pv[1],pv[2],pv[3]);
      *(float4*)(P + iq*36 + kq + 4) = make_float4(pv[4],pv[5],pv[6],pv[7]);
    }
    {
      const int jj = tid >> 4, kk = tid & 15;
      Qb[jj*32 + kk]      = sK[(j0+jj)*33 + kk]      * __expf(sG[j0*33 + kk]      - sG[(j0+jj)*33 + kk]);
      Qb[jj*32 + kk + 16] = sK[(j0+jj)*33 + kk + 16] * __expf(sG[j0*33 + kk + 16] - sG[(j0+jj)*33 + kk + 16]);
    }
    __syncthreads();
    float a0 = 0.f, a1 = 0.f, a2 = 0.f, a3 = 0.f;
    #pragma unroll
    for (int t8 = 0; t8 < 8; ++t8) {
      const int k0 = t8*4;
      const float4 pa = *(const float4*)(P  + i64*36 + k0);
      const float4 xa = *(const float4*)(Qb + (w4  )*32 + k0);
      const float4 xb = *(const float4*)(Qb + (w4+1)*32 + k0);
      const float4 xc = *(const float4*)(Qb + (w4+8)*32 + k0);
      const float4 xd = *(const float4*)(Qb + (w4+9)*32 + k0);
      a0 += pa.x*xa.x + pa.y*xa.y + pa.z*xa.z + pa.w*xa.w;
      a1 += pa.x*xb.x + pa.y*xb.y + pa.z*xb.z + pa.w*xb.w;
      a2 += pa.x*xc.x + pa.y*xc.y + pa.z*xc.z + pa.w*xc.w;
      a3 += pa.x*xd.x + pa.y*xd.y + pa.z*xd.z + pa.w*xd.w;
    }
    if (pL >= jt) {   // all 16 cols land in block-col jt
      float* Lb = sW + (pLb + jt)*256 + iL;
      Lb[(w4  )*16] = (i64 > j0+w4  ) ? a0*b_cm : 0.f;
      Lb[(w4+1)*16] = (i64 > j0+w4+1) ? a1*b_cm : 0.f;
      Lb[(w4+8)*16] = (i64 > j0+w4+8) ? a2*b_cm : 0.f;
      Lb[(w4+9)*16] = (i64 > j0+w4+9) ? a3*b_cm : 0.f;
    }
    __syncthreads();
  }

  // ---- Tm = (I+L)^-1: diag blocks ----
  if (tid < 64) {
    const int p = tid >> 4, col = tid & 15;
    const int bD = p*(p+1)/2 + p;
    float* Td = sU + bD*272;
    const float* Ld = sW + bD*256;
    Td[col] = (col == 0) ? 1.f : 0.f;   // row 0
    for (int i = 1; i < 16; ++i) {
      float acc = 0.f;
      for (int j = 0; j < i; ++j)
        acc -= Ld[j*16 + i] * Td[j*17 + col];
      Td[i*17 + col] = acc + ((i == col) ? 1.f : 0.f);
    }
  }
  __syncthreads();
  // off-diagonal: 2 waves x 3 rounds
  {
    const int wid = tid >> 6;
    const int lane = tid & 63;
    const int ri = lane & 15, c4 = (lane >> 4)*4;
    float* Ct = sW + 2560 + wid*272;
    auto offblk = [&](int p, int q) {
      const int pb = p*(p+1)/2;
      float a0=0.f, a1=0.f, a2=0.f, a3=0.f;
      for (int m = q; m < p; ++m) {
        const float* Lb = sW + (pb + m)*256;
        const float* Tb = sU + (m*(m+1)/2 + q)*272;
        #pragma unroll
        for (int j = 0; j < 16; ++j) {
          const float lv = Lb[j*16 + ri];
          const float* tp = Tb + j*17 + c4;
          a0 += lv*tp[0]; a1 += lv*tp[1]; a2 += lv*tp[2]; a3 += lv*tp[3];
        }
      }
      float* cp = Ct + ri*17 + c4;
      cp[0]=a0; cp[1]=a1; cp[2]=a2; cp[3]=a3;
      const float* Tpp = sU + (pb + p)*272 + ri*17;
      float b0=0.f, b1=0.f, b2=0.f, b3=0.f;
      #pragma unroll
      for (int j = 0; j < 16; ++j) {
        const float tv = Tpp[j];
        const float* cj = Ct + j*17 + c4;
        b0 += tv*cj[0]; b1 += tv*cj[1]; b2 += tv*cj[2]; b3 += tv*cj[3];
      }
      float* op = sU + (pb + q)*272 + ri*17 + c4;
      op[0]=-b0; op[1]=-b1; op[2]=-b2; op[3]=-b3;
    };
    if (wid == 0) offblk(1,0); else if (wid == 1) offblk(2,1);
    __syncthreads();
    if (wid == 0) offblk(2,0); else if (wid == 1) offblk(3,1);
    __syncthreads();
    if (wid == 0) offblk(3,0); else if (wid == 1) offblk(3,2);
  }
  __syncthreads();

  { // k_egb into sW[0..2048); kd -> sK; Egl @ sW+3072
    const float b_row = beta[((size_t)b*Tt + t0 + iq)*Hh + h];
    #pragma unroll
    for (int r = 0; r < 8; ++r) {
      const int idx = iq*33 + kq + r;
      const float g = sG[idx], kn = sK[idx];
      sW[iq*32 + kq + r] = b_row * kn * __expf(g);
      sK[idx] = kn * __expf(sG[63*33 + kq + r] - g);
    }
    if (tid < 32) sW[3072 + tid] = __expf(sG[63*33 + tid]);
  }
  __syncthreads();

  const int pT = iq >> 4, pTb = pT*(pT+1)/2;
  const int r17 = (iq & 15)*17, iqm = iq & 15;

  { // w = Tm @ k_egb -> global + sG (gcum dead)
    float acc[8] = {0,0,0,0,0,0,0,0};
    for (int m = 0; m <= pT; ++m) {
      const float* Tb = sU + (pTb + m)*272 + r17;
      const int jmax = (m == pT) ? iqm : 15;
      const float* eb = sW + m*16*32 + kq;
      for (int jj = 0; jj <= jmax; ++jj) {
        const float t = Tb[jj];
        const float4 e0 = *(const float4*)(eb + jj*32);
        const float4 e1 = *(const float4*)(eb + jj*32 + 4);
        acc[0]+=t*e0.x; acc[1]+=t*e0.y; acc[2]+=t*e0.z; acc[3]+=t*e0.w;
        acc[4]+=t*e1.x; acc[5]+=t*e1.y; acc[6]+=t*e1.z; acc[7]+=t*e1.w;
      }
    }
    #pragma unroll
    for (int r = 0; r < 8; ++r) {
      wsW[(size_t)ch*2048 + tid*8 + r] = acc[r];
      sG[iq*32 + kq + r] = acc[r];
    }
  }
  __syncthreads();   // k_egb reads done; w visible

  const int vs8 = (tid & 3)*8;
  for (int vh = 0; vh < 2; ++vh) {
    { // stage vb-half (64 x 32 cols)
      #pragma unroll
      for (int r = 0; r < 2; ++r) {
        const int f = tid + 256*r;
        const int j = f >> 3, cc = (f & 7)*4;
        const float bj = beta[((size_t)b*Tt + t0 + j)*Hh + h];
        float4 v4 = *(const float4*)(vin + (((size_t)b*Tt + t0 + j)*Hh + h)*64 + vh*32 + cc);
        v4.x *= bj; v4.y *= bj; v4.z *= bj; v4.w *= bj;
        *(float4*)(sW + j*32 + cc) = v4;
      }
    }
    __syncthreads();
    float ua[8];
    { // u-half = Tm @ vb-half -> wsU
      #pragma unroll
      for (int r = 0; r < 8; ++r) ua[r] = 0.f;
      for (int m = 0; m <= pT; ++m) {
        const float* Tb = sU + (pTb + m)*272 + r17;
        const int jmax = (m == pT) ? iqm : 15;
        const float* eb = sW + m*16*32 + vs8;
        for (int jj = 0; jj <= jmax; ++jj) {
          const float t = Tb[jj];
          const float4 e0 = *(const float4*)(eb + jj*32);
          const float4 e1 = *(const float4*)(eb + jj*32 + 4);
          ua[0]+=t*e0.x; ua[1]+=t*e0.y; ua[2]+=t*e0.z; ua[3]+=t*e0.w;
          ua[4]+=t*e1.x; ua[5]+=t*e1.y; ua[6]+=t*e1.z; ua[7]+=t*e1.w;
        }
      }
      *(float4*)(wsU + (size_t)ch*4096 + iq*64 + vh*32 + vs8)     = make_float4(ua[0],ua[1],ua[2],ua[3]);
      *(float4*)(wsU + (size_t)ch*4096 + iq*64 + vh*32 + vs8 + 4) = make_float4(ua[4],ua[5],ua[6],ua[7]);
    }
    __syncthreads();   // all vb reads done
    *(float4*)(sW + iq*32 + vs8)     = make_float4(ua[0],ua[1],ua[2],ua[3]);
    *(float4*)(sW + iq*32 + vs8 + 4) = make_float4(ua[4],ua[5],ua[6],ua[7]);
    __syncthreads();
    if (vh == 0) { // M = diag(egl) - Kd^T W (once)
      const int a = tid >> 3, b4 = (tid & 7)*4;
      float mA[4] = {0.f,0.f,0.f,0.f};
      for (int t = 0; t < 64; ++t) {
        const float kd = sK[t*33 + a];
        const float4 wv = *(const float4*)(sG + t*32 + b4);
        mA[0]+=kd*wv.x; mA[1]+=kd*wv.y; mA[2]+=kd*wv.z; mA[3]+=kd*wv.w;
      }
      const float eg = sW[3072 + a];
      float4 m4;
      m4.x = ((a == b4+0) ? eg : 0.f) - mA[0];
      m4.y = ((a == b4+1) ? eg : 0.f) - mA[1];
      m4.z = ((a == b4+2) ? eg : 0.f) - mA[2];
      m4.w = ((a == b4+3) ? eg : 0.f) - mA[3];
      *(float4*)(wsM + (size_t)ch*1024 + tid*4) = m4;
    }
    { // C-half = Kd^T U-half
      const int a = tid >> 3, c4c = (tid & 7)*4;
      float cA[4] = {0.f,0.f,0.f,0.f};
      for (int t = 0; t < 64; ++t) {
        const float kd = sK[t*33 + a];
        const float4 u4 = *(const float4*)(sW + t*32 + c4c);
        cA[0]+=kd*u4.x; cA[1]+=kd*u4.y; cA[2]+=kd*u4.z; cA[3]+=kd*u4.w;
      }
      *(float4*)(wsCc + (size_t)ch*2048 + a*64 + vh*32 + c4c) = make_float4(cA[0],cA[1],cA[2],cA[3]);
    }
    __syncthreads();   // C reads done before next stage
  }
}

// ---------------- scanA ----------------
__global__ __launch_bounds__(256) void kda_scanA(float* __restrict__ ws)
{
  __shared__ float sMa[32*33];
  __shared__ float sMc[32*33];
  __shared__ float sCa[32*18];
  const int tid = threadIdx.x;
  const int vt = blockIdx.x & 3, seg = (blockIdx.x >> 2) & 7, bh = blockIdx.x >> 5;
  const int v0 = vt*16;
  const int a = tid >> 3, b4 = (tid & 7)*4, c2 = (tid & 7)*2;
  const float* wsM = ws + OFF_M;
  const float* wsC = ws + OFF_C;

  #pragma unroll
  for (int r = 0; r < 4; ++r) sMa[a*33 + b4 + r] = (a == b4 + r) ? 1.f : 0.f;
  sCa[a*18 + c2] = 0.f; sCa[a*18 + c2 + 1] = 0.f;

  int ch = (seg*16)*32 + bh;
  float4 m4 = *(const float4*)(wsM + (size_t)ch*1024 + tid*4);
  float2 cc = *(const float2*)(wsC + (size_t)ch*2048 + a*64 + v0 + c2);

  for (int i = 0; i < 16; ++i) {
    sMc[a*33+b4+0]=m4.x; sMc[a*33+b4+1]=m4.y; sMc[a*33+b4+2]=m4.z; sMc[a*33+b4+3]=m4.w;
    __syncthreads();
    float4 m4n = m4; float2 ccn = cc;
    if (i < 15) {
      const int chn = (seg*16 + i + 1)*32 + bh;
      m4n = *(const float4*)(wsM + (size_t)chn*1024 + tid*4);
      ccn = *(const float2*)(wsC + (size_t)chn*2048 + a*64 + v0 + c2);
    }
    float cn0 = cc.x, cn1 = cc.y;
    float mn0=0.f, mn1=0.f, mn2=0.f, mn3=0.f;
    for (int bb = 0; bb < 32; ++bb) {
      const float m = sMc[a*33 + bb];
      const float2 s2 = *(const float2*)(sCa + bb*18 + c2);
      cn0 += m*s2.x; cn1 += m*s2.y;
      mn0 += m*sMa[bb*33+b4+0]; mn1 += m*sMa[bb*33+b4+1];
      mn2 += m*sMa[bb*33+b4+2]; mn3 += m*sMa[bb*33+b4+3];
    }
    __syncthreads();
    sCa[a*18+c2] = cn0; sCa[a*18+c2+1] = cn1;
    sMa[a*33+b4+0]=mn0; sMa[a*33+b4+1]=mn1; sMa[a*33+b4+2]=mn2; sMa[a*33+b4+3]=mn3;
    m4 = m4n; cc = ccn;
  }
  const size_t sid = (size_t)(bh*8 + seg);
  float* wsMs = ws + OFF_MS;
  float* wsCs = ws + OFF_CS;
  if (vt == 0) {
    #pragma unroll
    for (int r = 0; r < 4; ++r) wsMs[sid*1024 + tid*4 + r] = sMa[a*33+b4+r];
  }
  float2 co; co.x = sCa[a*18+c2]; co.y = sCa[a*18+c2+1];
  *(float2*)(wsCs + sid*2048 + a*64 + v0 + c2) = co;
}

// ---------------- scanB ----------------
__global__ __launch_bounds__(256) void kda_scanB(float* __restrict__ ws)
{
  __shared__ float sS[32*18];
  __shared__ float sM[32*33];
  const int tid = threadIdx.x;
  const int vt = blockIdx.x & 3, bh = blockIdx.x >> 2;
  const int v0 = vt*16;
  const int a = tid >> 3, b4 = (tid & 7)*4, c2 = (tid & 7)*2;
  const float* wsMs = ws + OFF_MS;
  const float* wsCs = ws + OFF_CS;
  float* wsSs = ws + OFF_SS;

  float s0 = 0.f, s1 = 0.f;
  sS[a*18 + c2] = 0.f; sS[a*18 + c2 + 1] = 0.f;
  const size_t sid0 = (size_t)(bh*8);
  float4 m4 = *(const float4*)(wsMs + sid0*1024 + tid*4);
  float2 cc = *(const float2*)(wsCs + sid0*2048 + a*64 + v0 + c2);

  for (int seg = 0; seg < 8; ++seg) {
    const size_t sid = (size_t)(bh*8 + seg);
    *(float2*)(wsSs + sid*2048 + a*64 + v0 + c2) = make_float2(s0, s1);
    sM[a*33+b4+0]=m4.x; sM[a*33+b4+1]=m4.y; sM[a*33+b4+2]=m4.z; sM[a*33+b4+3]=m4.w;
    __syncthreads();
    float4 m4n = m4; float2 ccn = cc;
    if (seg < 7) {
      m4n = *(const float4*)(wsMs + (sid+1)*1024 + tid*4);
      ccn = *(const float2*)(wsCs + (sid+1)*2048 + a*64 + v0 + c2);
    }
    float n0 = cc.x, n1 = cc.y;
    for (int bb = 0; bb < 32; ++bb) {
      const float m = sM[a*33 + bb];
      const float2 s2 = *(const float2*)(sS + bb*18 + c2);
      n0 += m*s2.x; n1 += m*s2.y;
    }
    __syncthreads();
    s0 = n0; s1 = n1;
    sS[a*18+c2] = s0; sS[a*18+c2+1] = s1;
    m4 = m4n; cc = ccn;
  }
}

// ---------------- scanC ----------------
__global__ __launch_bounds__(256) void kda_scanC(float* __restrict__ ws)
{
  __shared__ float sM[32*33];
  __shared__ float sS[32*18];
  const int tid = threadIdx.x;
  const int vt = blockIdx.x & 3, seg = (blockIdx.x >> 2) & 7, bh = blockIdx.x >> 5;
  const int v0 = vt*16;
  const int a = tid >> 3, b4 = (tid & 7)*4, c2 = (tid & 7)*2;
  const float* wsM = ws + OFF_M;
  float* wsC = ws + OFF_C;
  const float* wsSs = ws + OFF_SS;

  const size_t sid = (size_t)(bh*8 + seg);
  float s0, s1;
  {
    float2 sv = *(const float2*)(wsSs + sid*2048 + a*64 + v0 + c2);
    s0 = sv.x; s1 = sv.y;
    sS[a*18 + c2] = s0; sS[a*18 + c2 + 1] = s1;
  }
  int ch = (seg*16)*32 + bh;
  float4 m4 = *(const float4*)(wsM + (size_t)ch*1024 + tid*4);
  float2 cc = *(const float2*)(wsC + (size_t)ch*2048 + a*64 + v0 + c2);

  for (int i = 0; i < 16; ++i) {
    const int chc = (seg*16 + i)*32 + bh;
    sM[a*33+b4+0]=m4.x; sM[a*33+b4+1]=m4.y; sM[a*33+b4+2]=m4.z; sM[a*33+b4+3]=m4.w;
    *(float2*)(wsC + (size_t)chc*2048 + a*64 + v0 + c2) = make_float2(s0, s1);
    __syncthreads();
    float4 m4n = m4; float2 ccn = cc;
    if (i < 15) {
      const int chn = (seg*16 + i + 1)*32 + bh;
      m4n = *(const float4*)(wsM + (size_t)chn*1024 + tid*4);
      ccn = *(const float2*)(wsC + (size_t)chn*2048 + a*64 + v0 + c2);
    }
    float n0 = cc.x, n1 = cc.y;
    for (int bb = 0; bb < 32; ++bb) {
      const float m = sM[a*33 + bb];
      const float2 s2 = *(const float2*)(sS + bb*18 + c2);
      n0 += m*s2.x; n1 += m*s2.y;
    }
    __syncthreads();
    s0 = n0; s1 = n1;
    sS[a*18+c2] = s0; sS[a*18+c2+1] = s1;
    m4 = m4n; cc = ccn;
  }
}

// ---------------- Phase 3 ----------------
// Aqk in 16-col tiles (8 barriers vs 16); u staged in two row-halves; LDS 39.0KB.
__global__ __launch_bounds__(256) void kda_phase3(
    const float* __restrict__ qin, const float* __restrict__ kin,
    const float* __restrict__ graw,
    const float* __restrict__ A_log, const float* __restrict__ dt_bias,
    const float* __restrict__ ws, float* __restrict__ out)
{
  __shared__ float sG[64*33];   // gcum (s33) -> S (32x64, 2048)
  __shared__ float sQ[64*33];   // qn -> qeff
  __shared__ float sA[2720];    // Aqk packed (10x272)
  __shared__ float sV[2816];    // P(2304,s36)+Qb(16x32 @2304) -> w(2048) -> u-row-half(2048)

  const int tid = threadIdx.x;
  const int ch = blockIdx.x;
  const int c = ch >> 5, bh = ch & 31;
  const int b = bh >> 4, h = bh & 15;
  const int t0 = c*64;
  const int iq = tid >> 2, kq = (tid & 3)*8;

  const float* wsW = ws;            // w (64x32)
  const float* wsU = ws + OFF_U;    // u (64x64)
  const float* wsS = ws + OFF_C;    // entering S (32x64)

  const float negA = -__expf(A_log[h]);
  {
    const float* gr = graw + (((size_t)b*Tt + t0 + iq)*Hh + h)*32 + kq;
    const float* db = dt_bias + h*32 + kq;
    #pragma unroll
    for (int r = 0; r < 8; ++r)
      sG[iq*33 + kq + r] = negA * softplusf(gr[r] + db[r]);
  }
  __syncthreads();
  if (tid < 32) {
    float c0 = 0.f;
    for (int blk = 0; blk < 4; ++blk) {
      float v[16];
      #pragma unroll
      for (int i = 0; i < 16; ++i) v[i] = sG[(blk*16+i)*33 + tid];
      #pragma unroll
      for (int i = 0; i < 16; ++i) { c0 += v[i]; sG[(blk*16+i)*33 + tid] = c0; }
    }
  }
  float knr[8];
  {
    const float* qp = qin + (((size_t)b*Tt + t0 + iq)*Hh + h)*32 + kq;
    float qr[8]; float ssq = 0.f;
    #pragma unroll
    for (int r = 0; r < 8; ++r) { qr[r] = qp[r]; ssq += qr[r]*qr[r]; }
    ssq += __shfl_xor(ssq, 1); ssq += __shfl_xor(ssq, 2);
    const float scq = 0.17677669529663687f / fmaxf(sqrtf(ssq), 1e-6f);
    #pragma unroll
    for (int r = 0; r < 8; ++r) sQ[iq*33 + kq + r] = qr[r]*scq;

    const float* kp = kin + (((size_t)b*Tt + t0 + iq)*Hh + h)*32 + kq;
    float ssk = 0.f;
    #pragma unroll
    for (int r = 0; r < 8; ++r) { knr[r] = kp[r]; ssk += knr[r]*knr[r]; }
    ssk += __shfl_xor(ssk, 1); ssk += __shfl_xor(ssk, 2);
    const float sck = 1.f / fmaxf(sqrtf(ssk), 1e-6f);
    #pragma unroll
    for (int r = 0; r < 8; ++r) knr[r] *= sck;
  }
  __syncthreads();

  float* P  = sV;
  float* Qb = sV + 2304;   // 16x32
  const int i64 = tid & 63;
  const int w4 = (tid >> 6)*2;
  const int pL = i64 >> 4, pLb = pL*(pL+1)/2, iL = i64 & 15;
  for (int jt = 0; jt < 4; ++jt) {
    const int j0 = jt*16;
    {
      float pv[8];
      #pragma unroll
      for (int r = 0; r < 8; ++r) {
        const int idx = iq*33 + kq + r;
        pv[r] = sQ[idx] * __expf(fminf(sG[idx] - sG[j0*33 + kq + r], 0.f));
      }
      *(float4*)(P + iq*36 + kq)     = make_float4(pv[0],pv[1],pv[2],pv[3]);
      *(float4*)(P + iq*36 + kq + 4) = make_float4(pv[4],pv[5],pv[6],pv[7]);
    }
    if (iq >= j0 && iq < j0 + 16) {
      const int jj = iq - j0;
      #pragma unroll
      for (int r = 0; r < 8; ++r)
        Qb[jj*32 + kq + r] = knr[r] * __expf(sG[j0*33 + kq + r] - sG[iq*33 + kq + r]);
    }
    __syncthreads();
    float a0 = 0.f, a1 = 0.f, a2 = 0.f, a3 = 0.f;
    #pragma unroll
    for (int t8 = 0; t8 < 8; ++t8) {
      const int k0 = t8*4;
      const float4 pa = *(const float4*)(P  + i64*36 + k0);
      const float4 xa = *(const float4*)(Qb + (w4  )*32 + k0);
      const float4 xb = *(const float4*)(Qb + (w4+1)*32 + k0);
      const float4 xc = *(const float4*)(Qb + (w4+8)*32 + k0);
      const float4 xd = *(const float4*)(Qb + (w4+9)*32 + k0);
      a0 += pa.x*xa.x + pa.y*xa.y + pa.z*xa.z + pa.w*xa.w;
      a1 += pa.x*xb.x + pa.y*xb.y + pa.z*xb.z + pa.w*xb.w;
      a2 += pa.x*xc.x + pa.y*xc.y + pa.z*xc.z + pa.w*xc.w;
      a3 += pa.x*xd.x + pa.y*xd.y + pa.z*xd.z + pa.w*xd.w;
    }
    if (pL >= jt) {
      float* Ab = sA + (pLb + jt)*272 + iL*17;
      Ab[w4  ] = (i64 >= j0+w4  ) ? a0 : 0.f;   // inclusive diagonal
      Ab[w4+1] = (i64 >= j0+w4+1) ? a1 : 0.f;
      Ab[w4+8] = (i64 >= j0+w4+8) ? a2 : 0.f;
      Ab[w4+9] = (i64 >= j0+w4+9) ? a3 : 0.f;
    }
    __syncthreads();
  }

  float qgr[8];
  {
    #pragma unroll
    for (int r = 0; r < 8; ++r) {
      const int idx = iq*33 + kq + r;
      qgr[r] = sQ[idx] * __expf(sG[idx]);
    }
  }
  __syncthreads();   // gcum + P/Qb dead
  { // stage S into sG[0..2048) and w into sV[0..2048)
    #pragma unroll
    for (int rr = 0; rr < 2; ++rr) {
      const int f = tid + 256*rr;
      *(float4*)(sG + f*4) = *(const float4*)(wsS + (size_t)ch*2048 + f*4);
    }
    *(float4*)(sV + tid*8)     = *(const float4*)(wsW + (size_t)ch*2048 + tid*8);
    *(float4*)(sV + tid*8 + 4) = *(const float4*)(wsW + (size_t)ch*2048 + tid*8 + 4);
  }
  __syncthreads();
  const int pT = iq >> 4, pTb = pT*(pT+1)/2;
  const int r17 = (iq & 15)*17, iqm = iq & 15;
  { // qeff = qg - Aqk @ w  -> sQ
    float qe[8];
    #pragma unroll
    for (int r = 0; r < 8; ++r) qe[r] = qgr[r];
    for (int m = 0; m <= pT; ++m) {
      const float* Ab = sA + (pTb + m)*272 + r17;
      const int jmax = (m == pT) ? iqm : 15;
      const float* wb = sV + m*16*32 + kq;
      for (int jj = 0; jj <= jmax; ++jj) {
        const float av = Ab[jj];
        const float4 w0 = *(const float4*)(wb + jj*32);
        const float4 w1 = *(const float4*)(wb + jj*32 + 4);
        qe[0]-=av*w0.x; qe[1]-=av*w0.y; qe[2]-=av*w0.z; qe[3]-=av*w0.w;
        qe[4]-=av*w1.x; qe[5]-=av*w1.y; qe[6]-=av*w1.z; qe[7]-=av*w1.w;
      }
    }
    #pragma unroll
    for (int r = 0; r < 8; ++r) sQ[iq*33 + kq + r] = qe[r];
  }
  __syncthreads();   // qeff visible; w reads done

  { // o = qeff @ S + Aqk @ u, u staged in two row-halves (dense copies)
    const int vs = (tid & 3)*16;
    float acc[16];
    #pragma unroll
    for (int r = 0; r < 16; ++r) acc[r] = 0.f;
    for (int vh = 0; vh < 2; ++vh) {
      { // stage u rows [vh*32, vh*32+32): contiguous 8KB
        #pragma unroll
        for (int rr = 0; rr < 2; ++rr) {
          const int f = tid + 256*rr;
          *(float4*)(sV + f*4) = *(const float4*)(wsU + (size_t)ch*4096 + vh*2048 + f*4);
        }
      }
      __syncthreads();
      if (vh == 0) { // qeff @ S (once; independent of u)
        for (int kk = 0; kk < 32; ++kk) {
          const float qv = sQ[iq*33 + kk];
          const float4 s0 = *(const float4*)(sG + kk*64 + vs);
          const float4 s1 = *(const float4*)(sG + kk*64 + vs + 4);
          const float4 s2 = *(const float4*)(sG + kk*64 + vs + 8);
          const float4 s3 = *(const float4*)(sG + kk*64 + vs + 12);
          acc[0]+=qv*s0.x;  acc[1]+=qv*s0.y;  acc[2]+=qv*s0.z;  acc[3]+=qv*s0.w;
          acc[4]+=qv*s1.x;  acc[5]+=qv*s1.y;  acc[6]+=qv*s1.z;  acc[7]+=qv*s1.w;
          acc[8]+=qv*s2.x;  acc[9]+=qv*s2.y;  acc[10]+=qv*s2.z; acc[11]+=qv*s2.w;
          acc[12]+=qv*s3.x; acc[13]+=qv*s3.y; acc[14]+=qv*s3.z; acc[15]+=qv*s3.w;
        }
      }
      // Aqk @ u rows in this half: blocks m = vh*2, vh*2+1 (clipped to pT)
      for (int m = vh*2; m <= pT && m < vh*2 + 2; ++m) {
        const float* Ab = sA + (pTb + m)*272 + r17;
        const int jmax = (m == pT) ? iqm : 15;
        const float* ub = sV + (m - vh*2)*16*64 + vs;
        for (int jj = 0; jj <= jmax; ++jj) {
          const float av = Ab[jj];
          const float4 u0 = *(const float4*)(ub + jj*64);
          const float4 u1 = *(const float4*)(ub + jj*64 + 4);
          const float4 u2 = *(const float4*)(ub + jj*64 + 8);
          const float4 u3 = *(const float4*)(ub + jj*64 + 12);
          acc[0]+=av*u0.x;  acc[1]+=av*u0.y;  acc[2]+=av*u0.z;  acc[3]+=av*u0.w;
          acc[4]+=av*u1.x;  acc[5]+=av*u1.y;  acc[6]+=av*u1.z;  acc[7]+=av*u1.w;
          acc[8]+=av*u2.x;  acc[9]+=av*u2.y;  acc[10]+=av*u2.z; acc[11]+=av*u2.w;
          acc[12]+=av*u3.x; acc[13]+=av*u3.y; acc[14]+=av*u3.z; acc[15]+=av*u3.w;
        }
      }
      if (vh == 0) __syncthreads();   // u reads done before restage
    }
    float* op = out + (((size_t)b*Tt + t0 + iq)*Hh + h)*64 + vs;
    #pragma unroll
    for (int rr = 0; rr < 4; ++rr) {
      float4 o4; o4.x=acc[rr*4]; o4.y=acc[rr*4+1]; o4.z=acc[rr*4+2]; o4.w=acc[rr*4+3];
      *(float4*)(op + rr*4) = o4;
    }
  }
}

extern "C" void kernel_launch(void* const* d_in, const int* in_sizes, int n_in,
                              void* d_out, int out_size, void* d_ws, size_t ws_size,
                              hipStream_t stream) {
  const float* q    = (const float*)d_in[0];
  const float* k    = (const float*)d_in[1];
  const float* v    = (const float*)d_in[2];
  const float* graw = (const float*)d_in[3];
  const float* beta = (const float*)d_in[4];
  const float* A_log= (const float*)d_in[5];
  const float* dtb  = (const float*)d_in[6];
  float* out = (float*)d_out;
  float* ws  = (float*)d_ws;
  // requires ws_size >= 156.3 MB

  kda_phase1<<<NCH, 256, 0, stream>>>(k, v, graw, beta, A_log, dtb, ws);
  kda_scanA<<<1024, 256, 0, stream>>>(ws);
  kda_scanB<<<128, 256, 0, stream>>>(ws);
  kda_scanC<<<1024, 256, 0, stream>>>(ws);
  kda_phase3<<<NCH, 256, 0, stream>>>(q, k, graw, A_log, dtb, ws, out);
}